// Round 1
// baseline (298.896 us; speedup 1.0000x reference)
//
#include <hip/hip_runtime.h>
#include <hip/hip_bf16.h>

typedef __hip_bfloat16 bf16;
typedef unsigned short ushort;
typedef unsigned int uint;
typedef __attribute__((ext_vector_type(8))) short short8;
typedef __attribute__((ext_vector_type(4))) float f32x4;

#define Bsz 2
#define Tn  1536
#define Cn  1536
#define Hn  8
#define Kn  64
#define Vn  192
// H*K = 512, H*V = 1536, 2T-1 = 3071

__device__ __forceinline__ ushort f2bs(float f) {
  union { bf16 h; ushort u; } cv;
  cv.h = __float2bfloat16(f);
  return cv.u;
}
__device__ __forceinline__ float bs2f(ushort u) {
  union { float f; uint v; } cv; cv.v = ((uint)u) << 16; return cv.f;
}

// async global->LDS, 16B per lane; LDS dest = wave-uniform base + lane*16
__device__ __forceinline__ void gld_lds16(const ushort* g, ushort* l) {
  __builtin_amdgcn_global_load_lds(
      (const __attribute__((address_space(1))) uint*)g,
      (__attribute__((address_space(3))) uint*)l, 16, 0, 0);
}

// ---------------------------------------------------------------------------
// Merged prep kernel, grid (48,48,6):
//  z=0..3: transpose+cvt  W{q,k,v,o} f32 [1536][Cc] -> bf16 [Cc][1536]
//  z=4   : x f32 -> xb bf16 (vectorized x4, grid-stride)
//  z=5   : rk[r,c] bf16 from the Borzoi central-mask basis (double widths;
//          margins to integers >= 0.02 so no comparison flips vs fp32 ref).
// ---------------------------------------------------------------------------
__global__ __launch_bounds__(256) void prep(
    const float* __restrict__ x,  const float* __restrict__ Wq,
    const float* __restrict__ Wk, const float* __restrict__ Wv,
    const float* __restrict__ Wo, const float* __restrict__ Wr,
    ushort* __restrict__ xb, ushort* __restrict__ Wt,
    ushort* __restrict__ Wot, ushort* __restrict__ rkb) {
  const int z = blockIdx.z;
  if (z < 4) {
    if (z < 2 && blockIdx.x >= 16) return;
    const float* in = (z == 0) ? Wq : (z == 1) ? Wk : (z == 2) ? Wv : Wo;
    ushort* out = (z == 0) ? Wt : (z == 1) ? Wt + 512 * 1536
                : (z == 2) ? Wt + 1024 * 1536 : Wot;
    const int Cc = (z < 2) ? 512 : 1536;
    __shared__ float tile[32][33];
    const int bx = blockIdx.x * 32;
    const int by = blockIdx.y * 32;
    const int tx = threadIdx.x & 31, ty = threadIdx.x >> 5;
#pragma unroll
    for (int i = 0; i < 32; i += 8)
      tile[ty + i][tx] = in[(size_t)(by + ty + i) * Cc + bx + tx];
    __syncthreads();
#pragma unroll
    for (int i = 0; i < 32; i += 8)
      out[(size_t)(bx + ty + i) * 1536 + by + tx] = f2bs(tile[tx][ty + i]);
  } else if (z == 4) {
    const int n4 = 3072 * 1536 / 4;
    for (int i = (blockIdx.y * 48 + blockIdx.x) * 256 + threadIdx.x; i < n4;
         i += 2304 * 256) {
      float4 v = ((const float4*)x)[i];
      uint2 o;
      o.x = (uint)f2bs(v.x) | ((uint)f2bs(v.y) << 16);
      o.y = (uint)f2bs(v.z) | ((uint)f2bs(v.w) << 16);
      ((uint2*)xb)[i] = o;
    }
  } else {
    for (int u = blockIdx.y * 48 + blockIdx.x; u < 2 * 3071; u += 2304) {
      const int r = u >> 1;
      const int c = (u & 1) * 256 + threadIdx.x;
      const float d = (float)(r - (Tn - 1));
      const float ad = fabsf(d);
      const float sg = (d > 0.f) ? 1.f : ((d < 0.f) ? -1.f : 0.f);
      float acc = 0.f;
#pragma unroll
      for (int i = 0; i < 16; i++) {
        double cw = exp(log((double)(Tn + 1)) * (double)(i + 1) / 16.0) - 1.0;
        if ((float)cw > ad) acc += Wr[i * 512 + c] + sg * Wr[(16 + i) * 512 + c];
      }
      rkb[(size_t)r * 512 + c] = f2bs(acc);
    }
  }
}

// ---------------------------------------------------------------------------
// Fused QKV MFMA GEMM: xb @ Wt^T-layout -> qb/kb/vtb (m97 structure).
// ---------------------------------------------------------------------------
__global__ __launch_bounds__(256) void gemm_qkv(
    const ushort* __restrict__ xb, const ushort* __restrict__ Wt,
    ushort* __restrict__ qb, ushort* __restrict__ kb, ushort* __restrict__ vtb) {
  __shared__ ushort Al[128 * 32];
  __shared__ ushort Bl[128 * 32];
  const int tid = threadIdx.x;
  const int w = tid >> 6, lane = tid & 63, quad = lane >> 4, ln = lane & 15;
  const int bm = blockIdx.y * 128, bn = blockIdx.x * 128;
  const int wm = (w & 1) * 64, wn = (w >> 1) * 64;
  f32x4 acc[4][4];
#pragma unroll
  for (int i = 0; i < 4; i++)
#pragma unroll
    for (int j = 0; j < 4; j++) acc[i][j] = (f32x4){0.f, 0.f, 0.f, 0.f};

  for (int k0 = 0; k0 < 1536; k0 += 32) {
    __syncthreads();
#pragma unroll
    for (int st = 0; st < 2; st++) {
      int idx = tid + st * 256;
      int row = idx >> 2, col = (idx & 3) * 8;
      gld_lds16(xb + (size_t)(bm + row) * 1536 + k0 + col, Al + idx * 8);
      gld_lds16(Wt + (size_t)(bn + row) * 1536 + k0 + col, Bl + idx * 8);
    }
    __syncthreads();
    short8 af[4], bfr[4];
#pragma unroll
    for (int t = 0; t < 4; t++) {
      af[t]  = *(const short8*)(Al + (wm + t * 16 + ln) * 32 + quad * 8);
      bfr[t] = *(const short8*)(Bl + (wn + t * 16 + ln) * 32 + quad * 8);
    }
#pragma unroll
    for (int mt = 0; mt < 4; mt++)
#pragma unroll
      for (int nt = 0; nt < 4; nt++)
        acc[mt][nt] = __builtin_amdgcn_mfma_f32_16x16x32_bf16(
            af[mt], bfr[nt], acc[mt][nt], 0, 0, 0);
  }

  if (bn < 512) {
#pragma unroll
    for (int mt = 0; mt < 4; mt++)
#pragma unroll
      for (int nt = 0; nt < 4; nt++)
#pragma unroll
        for (int r = 0; r < 4; r++) {
          int m = bm + wm + mt * 16 + quad * 4 + r;
          int n = bn + wn + nt * 16 + ln;
          qb[(size_t)m * 512 + n] = f2bs(acc[mt][nt][r] * 0.125f);
        }
  } else if (bn < 1024) {
#pragma unroll
    for (int mt = 0; mt < 4; mt++)
#pragma unroll
      for (int nt = 0; nt < 4; nt++)
#pragma unroll
        for (int r = 0; r < 4; r++) {
          int m = bm + wm + mt * 16 + quad * 4 + r;
          int n = bn - 512 + wn + nt * 16 + ln;
          kb[(size_t)m * 512 + n] = f2bs(acc[mt][nt][r]);
        }
  } else {
#pragma unroll
    for (int mt = 0; mt < 4; mt++)
#pragma unroll
      for (int nt = 0; nt < 4; nt++) {
        int vcol = bn - 1024 + wn + nt * 16 + ln;
        int m0 = bm + wm + mt * 16 + quad * 4;
        uint2 val;
        val.x = (uint)f2bs(acc[mt][nt][0]) | ((uint)f2bs(acc[mt][nt][1]) << 16);
        val.y = (uint)f2bs(acc[mt][nt][2]) | ((uint)f2bs(acc[mt][nt][3]) << 16);
        *(uint2*)(vtb + (size_t)vcol * 3072 + m0) = val;
      }
  }
}

// ---------------------------------------------------------------------------
// Output MFMA GEMM: att(bf16) @ Wot + bo -> f32 out.
// ---------------------------------------------------------------------------
__global__ __launch_bounds__(256) void gemm_out(
    const ushort* __restrict__ att, const ushort* __restrict__ Wot,
    const float* __restrict__ bo, float* __restrict__ out) {
  __shared__ ushort Al[128 * 32];
  __shared__ ushort Bl[128 * 32];
  const int tid = threadIdx.x;
  const int w = tid >> 6, lane = tid & 63, quad = lane >> 4, ln = lane & 15;
  const int bm = blockIdx.y * 128, bn = blockIdx.x * 128;
  const int wm = (w & 1) * 64, wn = (w >> 1) * 64;
  f32x4 acc[4][4];
#pragma unroll
  for (int i = 0; i < 4; i++)
#pragma unroll
    for (int j = 0; j < 4; j++) acc[i][j] = (f32x4){0.f, 0.f, 0.f, 0.f};

  for (int k0 = 0; k0 < 1536; k0 += 32) {
    __syncthreads();
#pragma unroll
    for (int st = 0; st < 2; st++) {
      int idx = tid + st * 256;
      int row = idx >> 2, col = (idx & 3) * 8;
      gld_lds16(att + (size_t)(bm + row) * 1536 + k0 + col, Al + idx * 8);
      gld_lds16(Wot + (size_t)(bn + row) * 1536 + k0 + col, Bl + idx * 8);
    }
    __syncthreads();
    short8 af[4], bfr[4];
#pragma unroll
    for (int t = 0; t < 4; t++) {
      af[t]  = *(const short8*)(Al + (wm + t * 16 + ln) * 32 + quad * 8);
      bfr[t] = *(const short8*)(Bl + (wn + t * 16 + ln) * 32 + quad * 8);
    }
#pragma unroll
    for (int mt = 0; mt < 4; mt++)
#pragma unroll
      for (int nt = 0; nt < 4; nt++)
        acc[mt][nt] = __builtin_amdgcn_mfma_f32_16x16x32_bf16(
            af[mt], bfr[nt], acc[mt][nt], 0, 0, 0);
  }
#pragma unroll
  for (int mt = 0; mt < 4; mt++)
#pragma unroll
    for (int nt = 0; nt < 4; nt++)
#pragma unroll
      for (int r = 0; r < 4; r++) {
        int m = bm + wm + mt * 16 + quad * 4 + r;
        int n = bn + wn + nt * 16 + ln;
        out[(size_t)m * 1536 + n] = acc[mt][nt][r] + bo[n];
      }
}

// ---------------------------------------------------------------------------
// MFMA flash attention, split-K(x2), t-tile 64, 4 waves.
// XCD-AWARE SWIZZLE: linear block id L -> xcd = L&7 owns head h = xcd only.
//   g = L>>3; bsk = g/24 (b = bsk>>1, sk = bsk&1); t0 = (g%24)*64.
// Per-XCD L2 working set = one head's kb/vtb/rkb/qb slices (~2.3 MB < 4 MiB).
//
// v2 schedule (latency-bound fix, MfmaUtil was 13.8%):
//  - V is NOT staged: PV reads V fragments directly from global (L2-resident).
//    Removes the V-staging barrier pair + vmcnt(0) drain per tile.
//  - K/RK stay LDS-staged (single buffer, XOR-swizzled) but are PREFETCHED:
//    the DMA for tile ch+1 is issued right after the post-S barrier, so its
//    latency hides under softmax + PV (~700+ cyc) instead of a cold drain.
//  - 2 barriers/tile instead of 4.  s_setprio(1) around MFMA clusters (T5).
// LDS [38912B]: K[64]x128B @0, RK[128]x128B @8192;
//   per-wave 3584B scratch @24576: prl bf16[16][104] overlaid by Pp bf16[16][72].
// XOR swizzle (K/RK only): 16B chunk c of row r stored at physical chunk c^(r&7).
// Rel: j = (s-s0)-(t-t0)+63 in [0,127); wave w needs j-tiles 3-w..7-w (5).
// Partials: normalized O (bf16) + (m,l) per row; combined by attn_combine.
// ---------------------------------------------------------------------------
__global__ __launch_bounds__(256, 3) void attn_mfma(
    const ushort* __restrict__ qb, const ushort* __restrict__ kb,
    const ushort* __restrict__ vtb, const ushort* __restrict__ rkb,
    const float* __restrict__ rwb, const float* __restrict__ rrb,
    ushort* __restrict__ op0, ushort* __restrict__ op1,
    float2* __restrict__ mlb) {
  __shared__ __align__(16) char smem[38912];
  ushort* Kl  = (ushort*)smem;              // [64] rows x 128B
  ushort* RKl = (ushort*)(smem + 8192);     // [128] rows x 128B

  const int L  = blockIdx.x + 24 * blockIdx.y + 192 * blockIdx.z;
  const int h  = L & 7;                     // XCD id under round-robin
  const int g  = L >> 3;
  const int bsk = g / 24;
  const int b  = bsk >> 1;
  const int sk = bsk & 1;
  const int t0 = (g - bsk * 24) * 64;
  const int bT = b * Tn;
  const int tid = threadIdx.x;
  const int w = tid >> 6, lane = tid & 63, quad = lane >> 4, ln = lane & 15;

  ushort* prlb = (ushort*)(smem + 24576 + w * 3584);  // [16][104] bf16
  ushort* Pp   = (ushort*)(smem + 24576 + w * 3584);  // [16][72] bf16 (overlay)

  const int lr  = lane >> 3;          // staging: row-in-chunk 0..7
  const int lcx = (lane & 7) ^ lr;    // staging: logical 16B chunk (swizzle)

  // Q fragments (A-layout m=ln, k=quad*8+ks*32+e), + biases
  short8 qw8[2], qr8[2];
  {
    const ushort* qrow = qb + (size_t)(bT + t0 + 16 * w + ln) * 512 + h * 64;
#pragma unroll
    for (int ks = 0; ks < 2; ks++) {
      int k0 = quad * 8 + ks * 32;
#pragma unroll
      for (int e = 0; e < 8; e++) {
        float qv = bs2f(qrow[k0 + e]);
        qw8[ks][e] = (short)f2bs(qv + rwb[h * 64 + k0 + e]);
        qr8[ks][e] = (short)f2bs(qv + rrb[h * 64 + k0 + e]);
      }
    }
  }

  // per-lane V base: row = h*192 + ln (+16*vt later), col chunk = quad*8 (+ks*32)
  const ushort* vbase = vtb + (size_t)(h * 192 + ln) * 3072 + bT + quad * 8;

  f32x4 Oacc[12];
  float m_i[4], l_i[4];
#pragma unroll
  for (int vt = 0; vt < 12; vt++) Oacc[vt] = (f32x4){0.f, 0.f, 0.f, 0.f};
#pragma unroll
  for (int r = 0; r < 4; r++) { m_i[r] = -1e30f; l_i[r] = 0.f; }

  // ---- prologue: stage K/RK for ch = 0 ----
  {
    const int s0 = sk * 768;
    const int Dbase = s0 - t0 + 1472;
#pragma unroll
    for (int i = 0; i < 2; i++) {
      int kc = w * 2 + i, sr = kc * 8 + lr;
      gld_lds16(kb + (size_t)(bT + s0 + sr) * 512 + h * 64 + lcx * 8,
                (ushort*)(smem + kc * 1024) + lane * 8);
    }
#pragma unroll
    for (int i = 0; i < 4; i++) {
      int kc = w * 4 + i, j = kc * 8 + lr;
      int jr = Dbase + j; jr = jr > 3070 ? 3070 : jr;
      gld_lds16(rkb + (size_t)jr * 512 + h * 64 + lcx * 8,
                (ushort*)(smem + 8192 + kc * 1024) + lane * 8);
    }
  }
  __syncthreads();   // drains vmcnt -> K/RK(0) visible to all waves

  for (int ch = 0; ch < 12; ch++) {
    const int s0 = sk * 768 + ch * 64;

    // ---- S phase (reads Kl/RKl) ----
    f32x4 Sacc[4], Pacc[5];
    __builtin_amdgcn_s_setprio(1);
#pragma unroll
    for (int ct = 0; ct < 4; ct++) {
      Sacc[ct] = (f32x4){0.f, 0.f, 0.f, 0.f};
#pragma unroll
      for (int ks = 0; ks < 2; ks++) {
        short8 bfr = *(const short8*)(
            Kl + (16 * ct + ln) * 64 + ((quad + 4 * ks) ^ (ln & 7)) * 8);
        Sacc[ct] = __builtin_amdgcn_mfma_f32_16x16x32_bf16(qw8[ks], bfr, Sacc[ct], 0, 0, 0);
      }
    }
#pragma unroll
    for (int jtl = 0; jtl < 5; jtl++) {
      int jt = 3 - w + jtl;
      Pacc[jtl] = (f32x4){0.f, 0.f, 0.f, 0.f};
#pragma unroll
      for (int ks = 0; ks < 2; ks++) {
        short8 bfr = *(const short8*)(
            RKl + (16 * jt + ln) * 64 + ((quad + 4 * ks) ^ (ln & 7)) * 8);
        Pacc[jtl] = __builtin_amdgcn_mfma_f32_16x16x32_bf16(qr8[ks], bfr, Pacc[jtl], 0, 0, 0);
      }
    }
    __builtin_amdgcn_s_setprio(0);
    // rel logits (C-layout) -> per-wave prl (bf16); local col jl = 16*jtl + ln
#pragma unroll
    for (int jtl = 0; jtl < 5; jtl++)
#pragma unroll
      for (int r = 0; r < 4; r++)
        prlb[(4 * quad + r) * 104 + 16 * jtl + ln] = f2bs(Pacc[jtl][r]);

    __syncthreads();   // all waves done reading Kl/RKl (also drains prl writes)

    // ---- prefetch K/RK for ch+1 (latency hides under softmax + PV) ----
    if (ch < 11) {
      const int s0n = s0 + 64;
      const int Dbasen = s0n - t0 + 1472;
#pragma unroll
      for (int i = 0; i < 2; i++) {
        int kc = w * 2 + i, sr = kc * 8 + lr;
        gld_lds16(kb + (size_t)(bT + s0n + sr) * 512 + h * 64 + lcx * 8,
                  (ushort*)(smem + kc * 1024) + lane * 8);
      }
#pragma unroll
      for (int i = 0; i < 4; i++) {
        int kc = w * 4 + i, j = kc * 8 + lr;
        int jr = Dbasen + j; jr = jr > 3070 ? 3070 : jr;
        gld_lds16(rkb + (size_t)jr * 512 + h * 64 + lcx * 8,
                  (ushort*)(smem + 8192 + kc * 1024) + lane * 8);
      }
    }

    // ---- early V loads, group 0 (issue before softmax; T14) ----
    short8 vfr0[4][2];
#pragma unroll
    for (int vt = 0; vt < 4; vt++)
#pragma unroll
      for (int ks = 0; ks < 2; ks++)
        vfr0[vt][ks] = *(const short8*)(
            vbase + (size_t)(vt * 16) * 3072 + s0 + ks * 32);

    // gather: jl = 16ct + ln - row + 15 (row = wave-local q-row)
    float pS[4][4];
#pragma unroll
    for (int ct = 0; ct < 4; ct++)
#pragma unroll
      for (int r = 0; r < 4; r++) {
        int row = 4 * quad + r;
        pS[ct][r] = Sacc[ct][r] + bs2f(prlb[row * 104 + 16 * ct + ln - row + 15]);
      }
    // online softmax (row lives in the 16 lanes of this quad)
    float alpha[4];
#pragma unroll
    for (int r = 0; r < 4; r++) {
      float mx = fmaxf(fmaxf(pS[0][r], pS[1][r]), fmaxf(pS[2][r], pS[3][r]));
#pragma unroll
      for (int off = 8; off >= 1; off >>= 1) mx = fmaxf(mx, __shfl_xor(mx, off));
      float mnew = fmaxf(m_i[r], mx);
      alpha[r] = __expf(m_i[r] - mnew);
      m_i[r] = mnew;
      float rs = 0.f;
#pragma unroll
      for (int ct = 0; ct < 4; ct++) {
        pS[ct][r] = __expf(pS[ct][r] - mnew);
        rs += pS[ct][r];
      }
#pragma unroll
      for (int off = 8; off >= 1; off >>= 1) rs += __shfl_xor(rs, off);
      l_i[r] = l_i[r] * alpha[r] + rs;
    }
#pragma unroll
    for (int vt = 0; vt < 12; vt++)
#pragma unroll
      for (int r = 0; r < 4; r++) Oacc[vt][r] *= alpha[r];
    // probs -> Pp (bf16, overlays prl; all prl reads precede, same wave = safe)
#pragma unroll
    for (int ct = 0; ct < 4; ct++)
#pragma unroll
      for (int r = 0; r < 4; r++)
        Pp[(4 * quad + r) * 72 + 16 * ct + ln] = f2bs(pS[ct][r]);

    // ---- PV phase: V fragments direct from global (L2) ----
    short8 afr[2];
#pragma unroll
    for (int ks = 0; ks < 2; ks++)
      afr[ks] = *(const short8*)(Pp + ln * 72 + quad * 8 + ks * 32);
    __builtin_amdgcn_s_setprio(1);
#pragma unroll
    for (int vt = 0; vt < 4; vt++)
#pragma unroll
      for (int ks = 0; ks < 2; ks++)
        Oacc[vt] = __builtin_amdgcn_mfma_f32_16x16x32_bf16(
            afr[ks], vfr0[vt][ks], Oacc[vt], 0, 0, 0);
#pragma unroll
    for (int vg = 1; vg < 3; vg++) {
      short8 vfr[4][2];
#pragma unroll
      for (int vt4 = 0; vt4 < 4; vt4++)
#pragma unroll
        for (int ks = 0; ks < 2; ks++)
          vfr[vt4][ks] = *(const short8*)(
              vbase + (size_t)((vg * 4 + vt4) * 16) * 3072 + s0 + ks * 32);
#pragma unroll
      for (int vt4 = 0; vt4 < 4; vt4++)
#pragma unroll
        for (int ks = 0; ks < 2; ks++)
          Oacc[vg * 4 + vt4] = __builtin_amdgcn_mfma_f32_16x16x32_bf16(
              afr[ks], vfr[vt4][ks], Oacc[vg * 4 + vt4], 0, 0, 0);
    }
    __builtin_amdgcn_s_setprio(0);

    __syncthreads();   // own-vmcnt drained + barrier -> K/RK(ch+1) ready
  }

  // epilogue: normalized bf16 partial + (m,l)
  ushort* op = sk ? op1 : op0;
  float inv[4];
#pragma unroll
  for (int r = 0; r < 4; r++) inv[r] = 1.f / l_i[r];
#pragma unroll
  for (int vt = 0; vt < 12; vt++)
#pragma unroll
    for (int r = 0; r < 4; r++) {
      int t = t0 + 16 * w + 4 * quad + r;
      op[(size_t)(bT + t) * 1536 + h * 192 + 16 * vt + ln] = f2bs(Oacc[vt][r] * inv[r]);
    }
  if (ln == 0) {
#pragma unroll
    for (int r = 0; r < 4; r++) {
      int t = t0 + 16 * w + 4 * quad + r;
      float2 v; v.x = m_i[r]; v.y = l_i[r];
      mlb[((sk * 2 + b) * 8 + h) * 1536 + t] = v;
    }
  }
}

// ---------------------------------------------------------------------------
// Combine the two split-K partials: O = sum_i e^{m_i-M} l_i O_i / sum e^{m-M} l
// ---------------------------------------------------------------------------
__global__ __launch_bounds__(256) void attn_combine(
    const ushort* __restrict__ op0, const ushort* __restrict__ op1,
    const float2* __restrict__ mlb, ushort* __restrict__ att) {
  int g = blockIdx.x * 256 + threadIdx.x;   // group of 4 bf16
  int row = g / 384;                        // 0..3071
  int c4 = (g - row * 384) * 4;             // 0..1532
  int b = row >= 1536;
  int t = row - b * 1536;
  int h = c4 / 192;
  float2 ml0 = mlb[((0 + b) * 8 + h) * 1536 + t];
  float2 ml1 = mlb[((2 + b) * 8 + h) * 1536 + t];
  float M = fmaxf(ml0.x, ml1.x);
  float w0 = __expf(ml0.x - M) * ml0.y;
  float w1 = __expf(ml1.x - M) * ml1.y;
  float inv = 1.f / (w0 + w1);
  w0 *= inv; w1 *= inv;
  size_t off = (size_t)row * 1536 + c4;
  uint2 a = *(const uint2*)(op0 + off);
  uint2 c = *(const uint2*)(op1 + off);
  uint2 o;
  float r0 = w0 * bs2f((ushort)(a.x & 0xffff)) + w1 * bs2f((ushort)(c.x & 0xffff));
  float r1 = w0 * bs2f((ushort)(a.x >> 16))    + w1 * bs2f((ushort)(c.x >> 16));
  float r2 = w0 * bs2f((ushort)(a.y & 0xffff)) + w1 * bs2f((ushort)(c.y & 0xffff));
  float r3 = w0 * bs2f((ushort)(a.y >> 16))    + w1 * bs2f((ushort)(c.y >> 16));
  o.x = (uint)f2bs(r0) | ((uint)f2bs(r1) << 16);
  o.y = (uint)f2bs(r2) | ((uint)f2bs(r3) << 16);
  *(uint2*)(att + off) = o;
}

// ---------------------------------------------------------------------------
extern "C" void kernel_launch(void* const* d_in, const int* in_sizes, int n_in,
                              void* d_out, int out_size, void* d_ws, size_t ws_size,
                              hipStream_t stream) {
  const float* x   = (const float*)d_in[0];
  const float* Wq  = (const float*)d_in[1];
  const float* Wk  = (const float*)d_in[2];
  const float* Wv  = (const float*)d_in[3];
  const float* Wr  = (const float*)d_in[4];
  const float* rwb = (const float*)d_in[5];
  const float* rrb = (const float*)d_in[6];
  const float* Wo  = (const float*)d_in[7];
  const float* bo  = (const float*)d_in[8];
  float* out = (float*)d_out;

  char* ws = (char*)d_ws;
  // Region A [0, 9437184): xb (prep->qkv) -> op1 (attn) -> att (combine, same
  // addresses elementwise) -> gemm_out input.
  ushort* xb  = (ushort*)ws;
  ushort* op1 = (ushort*)ws;
  ushort* att = (ushort*)ws;
  ushort* Wot = (ushort*)(ws + 9437184);    // [1536][1536] bf16, until gemm_out
  ushort* Wt  = (ushort*)(ws + 14155776);   // [2560][1536] bf16, until gemm_qkv
  ushort* op0 = (ushort*)(ws + 14155776);   // overlays dead Wt (attn phase)
  ushort* qb  = (ushort*)(ws + 23592960);   // [3072][512] bf16 (scaled)
  ushort* kb  = (ushort*)(ws + 26738688);   // [3072][512] bf16
  ushort* vtb = (ushort*)(ws + 29884416);   // [1536][3072] bf16 (V^T)
  ushort* rkb = (ushort*)(ws + 39321600);   // [3071][512] bf16
  float2* mlb = (float2*)(ws + 42467328);   // [2][2][8][1536] (m,l)

  prep<<<dim3(48, 48, 6), dim3(256), 0, stream>>>(
      x, Wq, Wk, Wv, Wo, Wr, xb, Wt, Wot, rkb);
  gemm_qkv<<<dim3(20, 24), dim3(256), 0, stream>>>(xb, Wt, qb, kb, vtb);
  attn_mfma<<<dim3(24, 8, 4), dim3(256), 0, stream>>>(
      qb, kb, vtb, rkb, rwb, rrb, op0, op1, mlb);
  attn_combine<<<dim3(4608), dim3(256), 0, stream>>>(op0, op1, mlb, att);
  gemm_out<<<dim3(12, 24), dim3(256), 0, stream>>>(att, Wot, bo, out);
}

// Round 2
// 258.286 us; speedup vs baseline: 1.1572x; 1.1572x over previous
//
#include <hip/hip_runtime.h>
#include <hip/hip_bf16.h>

typedef __hip_bfloat16 bf16;
typedef unsigned short ushort;
typedef unsigned int uint;
typedef __attribute__((ext_vector_type(8))) short short8;
typedef __attribute__((ext_vector_type(4))) float f32x4;

#define Bsz 2
#define Tn  1536
#define Cn  1536
#define Hn  8
#define Kn  64
#define Vn  192
// H*K = 512, H*V = 1536, 2T-1 = 3071

__device__ __forceinline__ ushort f2bs(float f) {
  union { bf16 h; ushort u; } cv;
  cv.h = __float2bfloat16(f);
  return cv.u;
}
__device__ __forceinline__ float bs2f(ushort u) {
  union { float f; uint v; } cv; cv.v = ((uint)u) << 16; return cv.f;
}

// async global->LDS, 16B per lane; LDS dest = wave-uniform base + lane*16
__device__ __forceinline__ void gld_lds16(const ushort* g, ushort* l) {
  __builtin_amdgcn_global_load_lds(
      (const __attribute__((address_space(1))) uint*)g,
      (__attribute__((address_space(3))) uint*)l, 16, 0, 0);
}

// ---------------------------------------------------------------------------
// Merged prep kernel, grid (48,48,6):
//  z=0..3: transpose+cvt  W{q,k,v,o} f32 [1536][Cc] -> bf16 [Cc][1536]
//  z=4   : x f32 -> xb bf16 (vectorized x4, grid-stride)
//  z=5   : rk[r,c] bf16 from the Borzoi central-mask basis (double widths;
//          margins to integers >= 0.02 so no comparison flips vs fp32 ref).
// ---------------------------------------------------------------------------
__global__ __launch_bounds__(256) void prep(
    const float* __restrict__ x,  const float* __restrict__ Wq,
    const float* __restrict__ Wk, const float* __restrict__ Wv,
    const float* __restrict__ Wo, const float* __restrict__ Wr,
    ushort* __restrict__ xb, ushort* __restrict__ Wt,
    ushort* __restrict__ Wot, ushort* __restrict__ rkb) {
  const int z = blockIdx.z;
  if (z < 4) {
    if (z < 2 && blockIdx.x >= 16) return;
    const float* in = (z == 0) ? Wq : (z == 1) ? Wk : (z == 2) ? Wv : Wo;
    ushort* out = (z == 0) ? Wt : (z == 1) ? Wt + 512 * 1536
                : (z == 2) ? Wt + 1024 * 1536 : Wot;
    const int Cc = (z < 2) ? 512 : 1536;
    __shared__ float tile[32][33];
    const int bx = blockIdx.x * 32;
    const int by = blockIdx.y * 32;
    const int tx = threadIdx.x & 31, ty = threadIdx.x >> 5;
#pragma unroll
    for (int i = 0; i < 32; i += 8)
      tile[ty + i][tx] = in[(size_t)(by + ty + i) * Cc + bx + tx];
    __syncthreads();
#pragma unroll
    for (int i = 0; i < 32; i += 8)
      out[(size_t)(bx + ty + i) * 1536 + by + tx] = f2bs(tile[tx][ty + i]);
  } else if (z == 4) {
    const int n4 = 3072 * 1536 / 4;
    for (int i = (blockIdx.y * 48 + blockIdx.x) * 256 + threadIdx.x; i < n4;
         i += 2304 * 256) {
      float4 v = ((const float4*)x)[i];
      uint2 o;
      o.x = (uint)f2bs(v.x) | ((uint)f2bs(v.y) << 16);
      o.y = (uint)f2bs(v.z) | ((uint)f2bs(v.w) << 16);
      ((uint2*)xb)[i] = o;
    }
  } else {
    for (int u = blockIdx.y * 48 + blockIdx.x; u < 2 * 3071; u += 2304) {
      const int r = u >> 1;
      const int c = (u & 1) * 256 + threadIdx.x;
      const float d = (float)(r - (Tn - 1));
      const float ad = fabsf(d);
      const float sg = (d > 0.f) ? 1.f : ((d < 0.f) ? -1.f : 0.f);
      float acc = 0.f;
#pragma unroll
      for (int i = 0; i < 16; i++) {
        double cw = exp(log((double)(Tn + 1)) * (double)(i + 1) / 16.0) - 1.0;
        if ((float)cw > ad) acc += Wr[i * 512 + c] + sg * Wr[(16 + i) * 512 + c];
      }
      rkb[(size_t)r * 512 + c] = f2bs(acc);
    }
  }
}

// ---------------------------------------------------------------------------
// Fused QKV MFMA GEMM: xb @ Wt^T-layout -> qb/kb/vtb (m97 structure).
// ---------------------------------------------------------------------------
__global__ __launch_bounds__(256) void gemm_qkv(
    const ushort* __restrict__ xb, const ushort* __restrict__ Wt,
    ushort* __restrict__ qb, ushort* __restrict__ kb, ushort* __restrict__ vtb) {
  __shared__ ushort Al[128 * 32];
  __shared__ ushort Bl[128 * 32];
  const int tid = threadIdx.x;
  const int w = tid >> 6, lane = tid & 63, quad = lane >> 4, ln = lane & 15;
  const int bm = blockIdx.y * 128, bn = blockIdx.x * 128;
  const int wm = (w & 1) * 64, wn = (w >> 1) * 64;
  f32x4 acc[4][4];
#pragma unroll
  for (int i = 0; i < 4; i++)
#pragma unroll
    for (int j = 0; j < 4; j++) acc[i][j] = (f32x4){0.f, 0.f, 0.f, 0.f};

  for (int k0 = 0; k0 < 1536; k0 += 32) {
    __syncthreads();
#pragma unroll
    for (int st = 0; st < 2; st++) {
      int idx = tid + st * 256;
      int row = idx >> 2, col = (idx & 3) * 8;
      gld_lds16(xb + (size_t)(bm + row) * 1536 + k0 + col, Al + idx * 8);
      gld_lds16(Wt + (size_t)(bn + row) * 1536 + k0 + col, Bl + idx * 8);
    }
    __syncthreads();
    short8 af[4], bfr[4];
#pragma unroll
    for (int t = 0; t < 4; t++) {
      af[t]  = *(const short8*)(Al + (wm + t * 16 + ln) * 32 + quad * 8);
      bfr[t] = *(const short8*)(Bl + (wn + t * 16 + ln) * 32 + quad * 8);
    }
#pragma unroll
    for (int mt = 0; mt < 4; mt++)
#pragma unroll
      for (int nt = 0; nt < 4; nt++)
        acc[mt][nt] = __builtin_amdgcn_mfma_f32_16x16x32_bf16(
            af[mt], bfr[nt], acc[mt][nt], 0, 0, 0);
  }

  if (bn < 512) {
#pragma unroll
    for (int mt = 0; mt < 4; mt++)
#pragma unroll
      for (int nt = 0; nt < 4; nt++)
#pragma unroll
        for (int r = 0; r < 4; r++) {
          int m = bm + wm + mt * 16 + quad * 4 + r;
          int n = bn + wn + nt * 16 + ln;
          qb[(size_t)m * 512 + n] = f2bs(acc[mt][nt][r] * 0.125f);
        }
  } else if (bn < 1024) {
#pragma unroll
    for (int mt = 0; mt < 4; mt++)
#pragma unroll
      for (int nt = 0; nt < 4; nt++)
#pragma unroll
        for (int r = 0; r < 4; r++) {
          int m = bm + wm + mt * 16 + quad * 4 + r;
          int n = bn - 512 + wn + nt * 16 + ln;
          kb[(size_t)m * 512 + n] = f2bs(acc[mt][nt][r]);
        }
  } else {
#pragma unroll
    for (int mt = 0; mt < 4; mt++)
#pragma unroll
      for (int nt = 0; nt < 4; nt++) {
        int vcol = bn - 1024 + wn + nt * 16 + ln;
        int m0 = bm + wm + mt * 16 + quad * 4;
        uint2 val;
        val.x = (uint)f2bs(acc[mt][nt][0]) | ((uint)f2bs(acc[mt][nt][1]) << 16);
        val.y = (uint)f2bs(acc[mt][nt][2]) | ((uint)f2bs(acc[mt][nt][3]) << 16);
        *(uint2*)(vtb + (size_t)vcol * 3072 + m0) = val;
      }
  }
}

// ---------------------------------------------------------------------------
// Output MFMA GEMM: att(bf16) @ Wot + bo -> f32 out.
// ---------------------------------------------------------------------------
__global__ __launch_bounds__(256) void gemm_out(
    const ushort* __restrict__ att, const ushort* __restrict__ Wot,
    const float* __restrict__ bo, float* __restrict__ out) {
  __shared__ ushort Al[128 * 32];
  __shared__ ushort Bl[128 * 32];
  const int tid = threadIdx.x;
  const int w = tid >> 6, lane = tid & 63, quad = lane >> 4, ln = lane & 15;
  const int bm = blockIdx.y * 128, bn = blockIdx.x * 128;
  const int wm = (w & 1) * 64, wn = (w >> 1) * 64;
  f32x4 acc[4][4];
#pragma unroll
  for (int i = 0; i < 4; i++)
#pragma unroll
    for (int j = 0; j < 4; j++) acc[i][j] = (f32x4){0.f, 0.f, 0.f, 0.f};

  for (int k0 = 0; k0 < 1536; k0 += 32) {
    __syncthreads();
#pragma unroll
    for (int st = 0; st < 2; st++) {
      int idx = tid + st * 256;
      int row = idx >> 2, col = (idx & 3) * 8;
      gld_lds16(att + (size_t)(bm + row) * 1536 + k0 + col, Al + idx * 8);
      gld_lds16(Wot + (size_t)(bn + row) * 1536 + k0 + col, Bl + idx * 8);
    }
    __syncthreads();
    short8 af[4], bfr[4];
#pragma unroll
    for (int t = 0; t < 4; t++) {
      af[t]  = *(const short8*)(Al + (wm + t * 16 + ln) * 32 + quad * 8);
      bfr[t] = *(const short8*)(Bl + (wn + t * 16 + ln) * 32 + quad * 8);
    }
#pragma unroll
    for (int mt = 0; mt < 4; mt++)
#pragma unroll
      for (int nt = 0; nt < 4; nt++)
        acc[mt][nt] = __builtin_amdgcn_mfma_f32_16x16x32_bf16(
            af[mt], bfr[nt], acc[mt][nt], 0, 0, 0);
  }
#pragma unroll
  for (int mt = 0; mt < 4; mt++)
#pragma unroll
    for (int nt = 0; nt < 4; nt++)
#pragma unroll
      for (int r = 0; r < 4; r++) {
        int m = bm + wm + mt * 16 + quad * 4 + r;
        int n = bn + wn + nt * 16 + ln;
        out[(size_t)m * 1536 + n] = acc[mt][nt][r] + bo[n];
      }
}

// ---------------------------------------------------------------------------
// MFMA flash attention, split-K(x2), t-tile 64, 4 waves, DMA staging.
// XCD-AWARE SWIZZLE: linear block id L -> xcd = L&7 owns head h = xcd only.
//   g = L>>3; bsk = g/24 (b = bsk>>1, sk = bsk&1); t0 = (g%24)*64.
// Per-XCD L2 working set = one head's kb/vtb/rkb/qb slices (~2.3 MB < 4 MiB).
//
// v3 schedule: DISJOINT LDS buffers (no K/RK <-> V overlay) so staging
// pipelines instead of serializing. Per tile:
//   issue V(ch) DMA           (V buffer free since prev barrier#2)
//   S MFMAs on Kl/RKl         (covers V DMA latency)
//   barrier #1                (drains vmcnt -> V(ch) in LDS; all S reads done)
//   issue K/RK(ch+1) DMA      (Kl/RKl free after barrier #1)
//   gather + softmax + Pp
//   PV MFMAs on Vl/Pp         (covers K/RK DMA latency)
//   barrier #2                (drains vmcnt -> K/RK(ch+1) ready)
// 2 barriers/tile (v1 had 4); every vmcnt(0) drain is covered by compute.
// All staging is coalesced global_load_lds (v2's per-lane V loads regressed:
// uncoalesced rows + in-order vmcnt put prefetch on PV's critical path).
// LDS [63488B]: K[64]x128B @0, RK[128]x128B @8192, V[192]x128B @24576;
//   per-wave 3584B scratch @49152: prl bf16[16][104] overlaid by Pp bf16[16][72].
// XOR swizzle: 16B chunk c of row r stored at physical chunk c^(r&7).
// Rel: j = (s-s0)-(t-t0)+63 in [0,127); wave w needs j-tiles 3-w..7-w (5).
// Cost: 2 blocks/CU (was 3). Partials: normalized O (bf16) + (m,l) per row.
// ---------------------------------------------------------------------------
__global__ __launch_bounds__(256, 2) void attn_mfma(
    const ushort* __restrict__ qb, const ushort* __restrict__ kb,
    const ushort* __restrict__ vtb, const ushort* __restrict__ rkb,
    const float* __restrict__ rwb, const float* __restrict__ rrb,
    ushort* __restrict__ op0, ushort* __restrict__ op1,
    float2* __restrict__ mlb) {
  __shared__ __align__(16) char smem[63488];
  ushort* Kl  = (ushort*)smem;              // [64] rows x 128B @ 0
  ushort* RKl = (ushort*)(smem + 8192);     // [128] rows x 128B @ 8192
  ushort* Vl  = (ushort*)(smem + 24576);    // [192] rows x 128B @ 24576

  const int L  = blockIdx.x + 24 * blockIdx.y + 192 * blockIdx.z;
  const int h  = L & 7;                     // XCD id under round-robin
  const int g  = L >> 3;
  const int bsk = g / 24;
  const int b  = bsk >> 1;
  const int sk = bsk & 1;
  const int t0 = (g - bsk * 24) * 64;
  const int bT = b * Tn;
  const int tid = threadIdx.x;
  const int w = tid >> 6, lane = tid & 63, quad = lane >> 4, ln = lane & 15;

  ushort* prlb = (ushort*)(smem + 49152 + w * 3584);  // [16][104] bf16
  ushort* Pp   = (ushort*)(smem + 49152 + w * 3584);  // [16][72] bf16 (overlay)

  const int lr  = lane >> 3;          // staging: row-in-chunk 0..7
  const int lcx = (lane & 7) ^ lr;    // staging: logical 16B chunk (swizzle)

  // Q fragments (A-layout m=ln, k=quad*8+ks*32+e), + biases
  short8 qw8[2], qr8[2];
  {
    const ushort* qrow = qb + (size_t)(bT + t0 + 16 * w + ln) * 512 + h * 64;
#pragma unroll
    for (int ks = 0; ks < 2; ks++) {
      int k0 = quad * 8 + ks * 32;
#pragma unroll
      for (int e = 0; e < 8; e++) {
        float qv = bs2f(qrow[k0 + e]);
        qw8[ks][e] = (short)f2bs(qv + rwb[h * 64 + k0 + e]);
        qr8[ks][e] = (short)f2bs(qv + rrb[h * 64 + k0 + e]);
      }
    }
  }

  f32x4 Oacc[12];
  float m_i[4], l_i[4];
#pragma unroll
  for (int vt = 0; vt < 12; vt++) Oacc[vt] = (f32x4){0.f, 0.f, 0.f, 0.f};
#pragma unroll
  for (int r = 0; r < 4; r++) { m_i[r] = -1e30f; l_i[r] = 0.f; }

  // ---- prologue: stage K/RK for ch = 0 ----
  {
    const int s0 = sk * 768;
    const int Dbase = s0 - t0 + 1472;
#pragma unroll
    for (int i = 0; i < 2; i++) {
      int kc = w * 2 + i, sr = kc * 8 + lr;
      gld_lds16(kb + (size_t)(bT + s0 + sr) * 512 + h * 64 + lcx * 8,
                (ushort*)(smem + kc * 1024) + lane * 8);
    }
#pragma unroll
    for (int i = 0; i < 4; i++) {
      int kc = w * 4 + i, j = kc * 8 + lr;
      int jr = Dbase + j; jr = jr > 3070 ? 3070 : jr;
      gld_lds16(rkb + (size_t)jr * 512 + h * 64 + lcx * 8,
                (ushort*)(smem + 8192 + kc * 1024) + lane * 8);
    }
  }
  __syncthreads();   // K/RK(0) staged

  for (int ch = 0; ch < 12; ch++) {
    const int s0 = sk * 768 + ch * 64;

    // ---- issue V(ch) DMA (24 KB, 24 chunks; 6 per wave) into Vl ----
#pragma unroll
    for (int i = 0; i < 6; i++) {
      int kc = w * 6 + i, vr = kc * 8 + lr;
      gld_lds16(vtb + (size_t)(h * 192 + vr) * 3072 + bT + s0 + lcx * 8,
                (ushort*)(smem + 24576 + kc * 1024) + lane * 8);
    }

    // ---- S phase (reads Kl/RKl; covers V DMA latency) ----
    f32x4 Sacc[4], Pacc[5];
    __builtin_amdgcn_s_setprio(1);
#pragma unroll
    for (int ct = 0; ct < 4; ct++) {
      Sacc[ct] = (f32x4){0.f, 0.f, 0.f, 0.f};
#pragma unroll
      for (int ks = 0; ks < 2; ks++) {
        short8 bfr = *(const short8*)(
            Kl + (16 * ct + ln) * 64 + ((quad + 4 * ks) ^ (ln & 7)) * 8);
        Sacc[ct] = __builtin_amdgcn_mfma_f32_16x16x32_bf16(qw8[ks], bfr, Sacc[ct], 0, 0, 0);
      }
    }
#pragma unroll
    for (int jtl = 0; jtl < 5; jtl++) {
      int jt = 3 - w + jtl;
      Pacc[jtl] = (f32x4){0.f, 0.f, 0.f, 0.f};
#pragma unroll
      for (int ks = 0; ks < 2; ks++) {
        short8 bfr = *(const short8*)(
            RKl + (16 * jt + ln) * 64 + ((quad + 4 * ks) ^ (ln & 7)) * 8);
        Pacc[jtl] = __builtin_amdgcn_mfma_f32_16x16x32_bf16(qr8[ks], bfr, Pacc[jtl], 0, 0, 0);
      }
    }
    __builtin_amdgcn_s_setprio(0);
    // rel logits (C-layout) -> per-wave prl (bf16); local col jl = 16*jtl + ln
#pragma unroll
    for (int jtl = 0; jtl < 5; jtl++)
#pragma unroll
      for (int r = 0; r < 4; r++)
        prlb[(4 * quad + r) * 104 + 16 * jtl + ln] = f2bs(Pacc[jtl][r]);

    __syncthreads();   // #1: all S reads of Kl/RKl done; V(ch) drained into LDS

    // ---- issue K/RK(ch+1) DMA (latency hides under softmax + PV) ----
    if (ch < 11) {
      const int s0n = s0 + 64;
      const int Dbasen = s0n - t0 + 1472;
#pragma unroll
      for (int i = 0; i < 2; i++) {
        int kc = w * 2 + i, sr = kc * 8 + lr;
        gld_lds16(kb + (size_t)(bT + s0n + sr) * 512 + h * 64 + lcx * 8,
                  (ushort*)(smem + kc * 1024) + lane * 8);
      }
#pragma unroll
      for (int i = 0; i < 4; i++) {
        int kc = w * 4 + i, j = kc * 8 + lr;
        int jr = Dbasen + j; jr = jr > 3070 ? 3070 : jr;
        gld_lds16(rkb + (size_t)jr * 512 + h * 64 + lcx * 8,
                  (ushort*)(smem + 8192 + kc * 1024) + lane * 8);
      }
    }

    // gather: jl = 16ct + ln - row + 15 (row = wave-local q-row)
    float pS[4][4];
#pragma unroll
    for (int ct = 0; ct < 4; ct++)
#pragma unroll
      for (int r = 0; r < 4; r++) {
        int row = 4 * quad + r;
        pS[ct][r] = Sacc[ct][r] + bs2f(prlb[row * 104 + 16 * ct + ln - row + 15]);
      }
    // online softmax (row lives in the 16 lanes of this quad)
    float alpha[4];
#pragma unroll
    for (int r = 0; r < 4; r++) {
      float mx = fmaxf(fmaxf(pS[0][r], pS[1][r]), fmaxf(pS[2][r], pS[3][r]));
#pragma unroll
      for (int off = 8; off >= 1; off >>= 1) mx = fmaxf(mx, __shfl_xor(mx, off));
      float mnew = fmaxf(m_i[r], mx);
      alpha[r] = __expf(m_i[r] - mnew);
      m_i[r] = mnew;
      float rs = 0.f;
#pragma unroll
      for (int ct = 0; ct < 4; ct++) {
        pS[ct][r] = __expf(pS[ct][r] - mnew);
        rs += pS[ct][r];
      }
#pragma unroll
      for (int off = 8; off >= 1; off >>= 1) rs += __shfl_xor(rs, off);
      l_i[r] = l_i[r] * alpha[r] + rs;
    }
#pragma unroll
    for (int vt = 0; vt < 12; vt++)
#pragma unroll
      for (int r = 0; r < 4; r++) Oacc[vt][r] *= alpha[r];
    // probs -> Pp (bf16, overlays prl; all prl reads precede, same wave = safe)
#pragma unroll
    for (int ct = 0; ct < 4; ct++)
#pragma unroll
      for (int r = 0; r < 4; r++)
        Pp[(4 * quad + r) * 72 + 16 * ct + ln] = f2bs(pS[ct][r]);
    __asm__ volatile("s_waitcnt lgkmcnt(0)" ::: "memory");

    // ---- PV phase (reads Vl + Pp; covers K/RK(ch+1) DMA latency) ----
    short8 afr[2];
#pragma unroll
    for (int ks = 0; ks < 2; ks++)
      afr[ks] = *(const short8*)(Pp + ln * 72 + quad * 8 + ks * 32);
    __builtin_amdgcn_s_setprio(1);
#pragma unroll
    for (int vt = 0; vt < 12; vt++) {
#pragma unroll
      for (int ks = 0; ks < 2; ks++) {
        short8 bfr = *(const short8*)(
            Vl + (16 * vt + ln) * 64 + ((quad + 4 * ks) ^ (ln & 7)) * 8);
        Oacc[vt] = __builtin_amdgcn_mfma_f32_16x16x32_bf16(afr[ks], bfr, Oacc[vt], 0, 0, 0);
      }
    }
    __builtin_amdgcn_s_setprio(0);

    __syncthreads();   // #2: PV done (V buffer free); K/RK(ch+1) drained
  }

  // epilogue: normalized bf16 partial + (m,l)
  ushort* op = sk ? op1 : op0;
  float inv[4];
#pragma unroll
  for (int r = 0; r < 4; r++) inv[r] = 1.f / l_i[r];
#pragma unroll
  for (int vt = 0; vt < 12; vt++)
#pragma unroll
    for (int r = 0; r < 4; r++) {
      int t = t0 + 16 * w + 4 * quad + r;
      op[(size_t)(bT + t) * 1536 + h * 192 + 16 * vt + ln] = f2bs(Oacc[vt][r] * inv[r]);
    }
  if (ln == 0) {
#pragma unroll
    for (int r = 0; r < 4; r++) {
      int t = t0 + 16 * w + 4 * quad + r;
      float2 v; v.x = m_i[r]; v.y = l_i[r];
      mlb[((sk * 2 + b) * 8 + h) * 1536 + t] = v;
    }
  }
}

// ---------------------------------------------------------------------------
// Combine the two split-K partials: O = sum_i e^{m_i-M} l_i O_i / sum e^{m-M} l
// ---------------------------------------------------------------------------
__global__ __launch_bounds__(256) void attn_combine(
    const ushort* __restrict__ op0, const ushort* __restrict__ op1,
    const float2* __restrict__ mlb, ushort* __restrict__ att) {
  int g = blockIdx.x * 256 + threadIdx.x;   // group of 4 bf16
  int row = g / 384;                        // 0..3071
  int c4 = (g - row * 384) * 4;             // 0..1532
  int b = row >= 1536;
  int t = row - b * 1536;
  int h = c4 / 192;
  float2 ml0 = mlb[((0 + b) * 8 + h) * 1536 + t];
  float2 ml1 = mlb[((2 + b) * 8 + h) * 1536 + t];
  float M = fmaxf(ml0.x, ml1.x);
  float w0 = __expf(ml0.x - M) * ml0.y;
  float w1 = __expf(ml1.x - M) * ml1.y;
  float inv = 1.f / (w0 + w1);
  w0 *= inv; w1 *= inv;
  size_t off = (size_t)row * 1536 + c4;
  uint2 a = *(const uint2*)(op0 + off);
  uint2 c = *(const uint2*)(op1 + off);
  uint2 o;
  float r0 = w0 * bs2f((ushort)(a.x & 0xffff)) + w1 * bs2f((ushort)(c.x & 0xffff));
  float r1 = w0 * bs2f((ushort)(a.x >> 16))    + w1 * bs2f((ushort)(c.x >> 16));
  float r2 = w0 * bs2f((ushort)(a.y & 0xffff)) + w1 * bs2f((ushort)(c.y & 0xffff));
  float r3 = w0 * bs2f((ushort)(a.y >> 16))    + w1 * bs2f((ushort)(c.y >> 16));
  o.x = (uint)f2bs(r0) | ((uint)f2bs(r1) << 16);
  o.y = (uint)f2bs(r2) | ((uint)f2bs(r3) << 16);
  *(uint2*)(att + off) = o;
}

// ---------------------------------------------------------------------------
extern "C" void kernel_launch(void* const* d_in, const int* in_sizes, int n_in,
                              void* d_out, int out_size, void* d_ws, size_t ws_size,
                              hipStream_t stream) {
  const float* x   = (const float*)d_in[0];
  const float* Wq  = (const float*)d_in[1];
  const float* Wk  = (const float*)d_in[2];
  const float* Wv  = (const float*)d_in[3];
  const float* Wr  = (const float*)d_in[4];
  const float* rwb = (const float*)d_in[5];
  const float* rrb = (const float*)d_in[6];
  const float* Wo  = (const float*)d_in[7];
  const float* bo  = (const float*)d_in[8];
  float* out = (float*)d_out;

  char* ws = (char*)d_ws;
  // Region A [0, 9437184): xb (prep->qkv) -> op1 (attn) -> att (combine, same
  // addresses elementwise) -> gemm_out input.
  ushort* xb  = (ushort*)ws;
  ushort* op1 = (ushort*)ws;
  ushort* att = (ushort*)ws;
  ushort* Wot = (ushort*)(ws + 9437184);    // [1536][1536] bf16, until gemm_out
  ushort* Wt  = (ushort*)(ws + 14155776);   // [2560][1536] bf16, until gemm_qkv
  ushort* op0 = (ushort*)(ws + 14155776);   // overlays dead Wt (attn phase)
  ushort* qb  = (ushort*)(ws + 23592960);   // [3072][512] bf16 (scaled)
  ushort* kb  = (ushort*)(ws + 26738688);   // [3072][512] bf16
  ushort* vtb = (ushort*)(ws + 29884416);   // [1536][3072] bf16 (V^T)
  ushort* rkb = (ushort*)(ws + 39321600);   // [3071][512] bf16
  float2* mlb = (float2*)(ws + 42467328);   // [2][2][8][1536] (m,l)

  prep<<<dim3(48, 48, 6), dim3(256), 0, stream>>>(
      x, Wq, Wk, Wv, Wo, Wr, xb, Wt, Wot, rkb);
  gemm_qkv<<<dim3(20, 24), dim3(256), 0, stream>>>(xb, Wt, qb, kb, vtb);
  attn_mfma<<<dim3(24, 8, 4), dim3(256), 0, stream>>>(
      qb, kb, vtb, rkb, rwb, rrb, op0, op1, mlb);
  attn_combine<<<dim3(4608), dim3(256), 0, stream>>>(op0, op1, mlb, att);
  gemm_out<<<dim3(12, 24), dim3(256), 0, stream>>>(att, Wot, bo, out);
}

// Round 3
// 254.201 us; speedup vs baseline: 1.1758x; 1.0161x over previous
//
#include <hip/hip_runtime.h>
#include <hip/hip_bf16.h>

typedef __hip_bfloat16 bf16;
typedef unsigned short ushort;
typedef unsigned int uint;
typedef __attribute__((ext_vector_type(8))) short short8;
typedef __attribute__((ext_vector_type(4))) float f32x4;

#define Bsz 2
#define Tn  1536
#define Cn  1536
#define Hn  8
#define Kn  64
#define Vn  192
// H*K = 512, H*V = 1536, 2T-1 = 3071

__device__ __forceinline__ ushort f2bs(float f) {
  union { bf16 h; ushort u; } cv;
  cv.h = __float2bfloat16(f);
  return cv.u;
}
__device__ __forceinline__ float bs2f(ushort u) {
  union { float f; uint v; } cv; cv.v = ((uint)u) << 16; return cv.f;
}

// async global->LDS, 16B per lane; LDS dest = wave-uniform base + lane*16
__device__ __forceinline__ void gld_lds16(const ushort* g, ushort* l) {
  __builtin_amdgcn_global_load_lds(
      (const __attribute__((address_space(1))) uint*)g,
      (__attribute__((address_space(3))) uint*)l, 16, 0, 0);
}

// ---------------------------------------------------------------------------
// Merged prep kernel, grid (48,48,6):
//  z=0..3: transpose+cvt  W{q,k,v,o} f32 [1536][Cc] -> bf16 [Cc][1536]
//  z=4   : x f32 -> xb bf16 (vectorized x4, grid-stride)
//  z=5   : rkd[8][40][64] bf16 (33 DISTINCT rel-basis rows per head: the
//          central-mask basis is a step function of |d| -> only 16 buckets
//          x sign +-, + d=0) and lutb[3072] u8: d+1535 -> row index u.
//          Same double-precision width math as before (no comparison flips).
// ---------------------------------------------------------------------------
__global__ __launch_bounds__(256) void prep(
    const float* __restrict__ x,  const float* __restrict__ Wq,
    const float* __restrict__ Wk, const float* __restrict__ Wv,
    const float* __restrict__ Wo, const float* __restrict__ Wr,
    ushort* __restrict__ xb, ushort* __restrict__ Wt,
    ushort* __restrict__ Wot, ushort* __restrict__ rkdb,
    unsigned char* __restrict__ lutb) {
  const int z = blockIdx.z;
  if (z < 4) {
    if (z < 2 && blockIdx.x >= 16) return;
    const float* in = (z == 0) ? Wq : (z == 1) ? Wk : (z == 2) ? Wv : Wo;
    ushort* out = (z == 0) ? Wt : (z == 1) ? Wt + 512 * 1536
                : (z == 2) ? Wt + 1024 * 1536 : Wot;
    const int Cc = (z < 2) ? 512 : 1536;
    __shared__ float tile[32][33];
    const int bx = blockIdx.x * 32;
    const int by = blockIdx.y * 32;
    const int tx = threadIdx.x & 31, ty = threadIdx.x >> 5;
#pragma unroll
    for (int i = 0; i < 32; i += 8)
      tile[ty + i][tx] = in[(size_t)(by + ty + i) * Cc + bx + tx];
    __syncthreads();
#pragma unroll
    for (int i = 0; i < 32; i += 8)
      out[(size_t)(bx + ty + i) * 1536 + by + tx] = f2bs(tile[tx][ty + i]);
  } else if (z == 4) {
    const int n4 = 3072 * 1536 / 4;
    for (int i = (blockIdx.y * 48 + blockIdx.x) * 256 + threadIdx.x; i < n4;
         i += 2304 * 256) {
      float4 v = ((const float4*)x)[i];
      uint2 o;
      o.x = (uint)f2bs(v.x) | ((uint)f2bs(v.y) << 16);
      o.y = (uint)f2bs(v.z) | ((uint)f2bs(v.w) << 16);
      ((uint2*)xb)[i] = o;
    }
  } else {
    const int base = (blockIdx.y * 48 + blockIdx.x) * 256 + threadIdx.x;
    if (base < 8 * 40 * 64) {
      // rkd entry: h, u-row (pad 33..39 = 0), k
      const int h = base / 2560, rem = base % 2560, u = rem >> 6, k = rem & 63;
      float acc = 0.f;
      if (u < 33) {
        const float sg = (u == 32) ? 0.f : (u < 16 ? 1.f : -1.f);
        const int c = (u == 32) ? 16 : (u < 16 ? u + 1 : u - 15);
        // active features are the c LARGEST widths: i = 16-c .. 15 (ascending,
        // same summation order as the original rkb builder)
#pragma unroll
        for (int i = 0; i < 16; i++)
          if (i >= 16 - c)
            acc += Wr[i * 512 + h * 64 + k] + sg * Wr[(16 + i) * 512 + h * 64 + k];
      }
      rkdb[h * 2560 + u * 64 + k] = f2bs(acc);
    } else if (base < 8 * 40 * 64 + 3072) {
      const int idx = base - 8 * 40 * 64;       // 0..3071 (3071 = pad)
      const int d = idx - 1535;
      const float ad = fabsf((float)d);
      int c = 0;
#pragma unroll
      for (int i = 0; i < 16; i++) {
        double cw = exp(log((double)(Tn + 1)) * (double)(i + 1) / 16.0) - 1.0;
        if ((float)cw > ad) c++;
      }
      lutb[idx] = (unsigned char)((d == 0) ? 32 : (d > 0 ? c - 1 : 15 + c));
    }
  }
}

// ---------------------------------------------------------------------------
// Fused QKV MFMA GEMM: xb @ Wt^T-layout -> qb/kb/vtb (m97 structure).
// ---------------------------------------------------------------------------
__global__ __launch_bounds__(256) void gemm_qkv(
    const ushort* __restrict__ xb, const ushort* __restrict__ Wt,
    ushort* __restrict__ qb, ushort* __restrict__ kb, ushort* __restrict__ vtb) {
  __shared__ ushort Al[128 * 32];
  __shared__ ushort Bl[128 * 32];
  const int tid = threadIdx.x;
  const int w = tid >> 6, lane = tid & 63, quad = lane >> 4, ln = lane & 15;
  const int bm = blockIdx.y * 128, bn = blockIdx.x * 128;
  const int wm = (w & 1) * 64, wn = (w >> 1) * 64;
  f32x4 acc[4][4];
#pragma unroll
  for (int i = 0; i < 4; i++)
#pragma unroll
    for (int j = 0; j < 4; j++) acc[i][j] = (f32x4){0.f, 0.f, 0.f, 0.f};

  for (int k0 = 0; k0 < 1536; k0 += 32) {
    __syncthreads();
#pragma unroll
    for (int st = 0; st < 2; st++) {
      int idx = tid + st * 256;
      int row = idx >> 2, col = (idx & 3) * 8;
      gld_lds16(xb + (size_t)(bm + row) * 1536 + k0 + col, Al + idx * 8);
      gld_lds16(Wt + (size_t)(bn + row) * 1536 + k0 + col, Bl + idx * 8);
    }
    __syncthreads();
    short8 af[4], bfr[4];
#pragma unroll
    for (int t = 0; t < 4; t++) {
      af[t]  = *(const short8*)(Al + (wm + t * 16 + ln) * 32 + quad * 8);
      bfr[t] = *(const short8*)(Bl + (wn + t * 16 + ln) * 32 + quad * 8);
    }
#pragma unroll
    for (int mt = 0; mt < 4; mt++)
#pragma unroll
      for (int nt = 0; nt < 4; nt++)
        acc[mt][nt] = __builtin_amdgcn_mfma_f32_16x16x32_bf16(
            af[mt], bfr[nt], acc[mt][nt], 0, 0, 0);
  }

  if (bn < 512) {
#pragma unroll
    for (int mt = 0; mt < 4; mt++)
#pragma unroll
      for (int nt = 0; nt < 4; nt++)
#pragma unroll
        for (int r = 0; r < 4; r++) {
          int m = bm + wm + mt * 16 + quad * 4 + r;
          int n = bn + wn + nt * 16 + ln;
          qb[(size_t)m * 512 + n] = f2bs(acc[mt][nt][r] * 0.125f);
        }
  } else if (bn < 1024) {
#pragma unroll
    for (int mt = 0; mt < 4; mt++)
#pragma unroll
      for (int nt = 0; nt < 4; nt++)
#pragma unroll
        for (int r = 0; r < 4; r++) {
          int m = bm + wm + mt * 16 + quad * 4 + r;
          int n = bn - 512 + wn + nt * 16 + ln;
          kb[(size_t)m * 512 + n] = f2bs(acc[mt][nt][r]);
        }
  } else {
#pragma unroll
    for (int mt = 0; mt < 4; mt++)
#pragma unroll
      for (int nt = 0; nt < 4; nt++) {
        int vcol = bn - 1024 + wn + nt * 16 + ln;
        int m0 = bm + wm + mt * 16 + quad * 4;
        uint2 val;
        val.x = (uint)f2bs(acc[mt][nt][0]) | ((uint)f2bs(acc[mt][nt][1]) << 16);
        val.y = (uint)f2bs(acc[mt][nt][2]) | ((uint)f2bs(acc[mt][nt][3]) << 16);
        *(uint2*)(vtb + (size_t)vcol * 3072 + m0) = val;
      }
  }
}

// ---------------------------------------------------------------------------
// D table: D[b][h][t][u] = (q_scaled[t] + rrb) . rkd[h][u]  (u < 33, pad 40)
// Same numeric pipeline as the old rel path: bf16(q+rrb) x bf16(rkd), f32 acc,
// bf16 store. Tiny kernel (~100 MFLOP); global reads are L1/L2 broadcast.
// ---------------------------------------------------------------------------
__global__ __launch_bounds__(256) void dgemm(
    const ushort* __restrict__ qb, const float* __restrict__ rrb,
    const ushort* __restrict__ rkdb, ushort* __restrict__ Db) {
  const int t0 = blockIdx.x * 64, h = blockIdx.y, b = blockIdx.z;
  const int t = t0 + (threadIdx.x >> 2), uu = threadIdx.x & 3;
  const ushort* qrow = qb + (size_t)(b * Tn + t) * 512 + h * 64;
  float qf[64];
#pragma unroll
  for (int k8 = 0; k8 < 8; k8++) {
    short8 v = *(const short8*)(qrow + k8 * 8);
#pragma unroll
    for (int e = 0; e < 8; e++)
      qf[k8 * 8 + e] = bs2f(f2bs(bs2f((ushort)v[e]) + rrb[h * 64 + k8 * 8 + e]));
  }
#pragma unroll
  for (int j = 0; j < 9; j++) {
    int u = uu + 4 * j;
    if (u < 33) {
      float acc = 0.f;
#pragma unroll
      for (int k8 = 0; k8 < 8; k8++) {
        short8 rv = *(const short8*)(rkdb + h * 2560 + u * 64 + k8 * 8);
#pragma unroll
        for (int e = 0; e < 8; e++)
          acc += qf[k8 * 8 + e] * bs2f((ushort)rv[e]);
      }
      Db[((size_t)(b * 8 + h) * 1536 + t) * 40 + u] = f2bs(acc);
    }
  }
}

// ---------------------------------------------------------------------------
// Output MFMA GEMM: att(bf16) @ Wot + bo -> f32 out.
// ---------------------------------------------------------------------------
__global__ __launch_bounds__(256) void gemm_out(
    const ushort* __restrict__ att, const ushort* __restrict__ Wot,
    const float* __restrict__ bo, float* __restrict__ out) {
  __shared__ ushort Al[128 * 32];
  __shared__ ushort Bl[128 * 32];
  const int tid = threadIdx.x;
  const int w = tid >> 6, lane = tid & 63, quad = lane >> 4, ln = lane & 15;
  const int bm = blockIdx.y * 128, bn = blockIdx.x * 128;
  const int wm = (w & 1) * 64, wn = (w >> 1) * 64;
  f32x4 acc[4][4];
#pragma unroll
  for (int i = 0; i < 4; i++)
#pragma unroll
    for (int j = 0; j < 4; j++) acc[i][j] = (f32x4){0.f, 0.f, 0.f, 0.f};

  for (int k0 = 0; k0 < 1536; k0 += 32) {
    __syncthreads();
#pragma unroll
    for (int st = 0; st < 2; st++) {
      int idx = tid + st * 256;
      int row = idx >> 2, col = (idx & 3) * 8;
      gld_lds16(att + (size_t)(bm + row) * 1536 + k0 + col, Al + idx * 8);
      gld_lds16(Wot + (size_t)(bn + row) * 1536 + k0 + col, Bl + idx * 8);
    }
    __syncthreads();
    short8 af[4], bfr[4];
#pragma unroll
    for (int t = 0; t < 4; t++) {
      af[t]  = *(const short8*)(Al + (wm + t * 16 + ln) * 32 + quad * 8);
      bfr[t] = *(const short8*)(Bl + (wn + t * 16 + ln) * 32 + quad * 8);
    }
#pragma unroll
    for (int mt = 0; mt < 4; mt++)
#pragma unroll
      for (int nt = 0; nt < 4; nt++)
        acc[mt][nt] = __builtin_amdgcn_mfma_f32_16x16x32_bf16(
            af[mt], bfr[nt], acc[mt][nt], 0, 0, 0);
  }
#pragma unroll
  for (int mt = 0; mt < 4; mt++)
#pragma unroll
    for (int nt = 0; nt < 4; nt++)
#pragma unroll
      for (int r = 0; r < 4; r++) {
        int m = bm + wm + mt * 16 + quad * 4 + r;
        int n = bn + wn + nt * 16 + ln;
        out[(size_t)m * 1536 + n] = acc[mt][nt][r] + bo[n];
      }
}

// ---------------------------------------------------------------------------
// MFMA flash attention, split-K(x2), t-tile 64, 4 waves, DMA staging.
// XCD-AWARE SWIZZLE: linear block id L -> xcd = L&7 owns head h = xcd only.
//
// v4: the rel-logit path is ELIMINATED (LDS-BW bound fix). rel[t][s] =
// D[t][lut(s-t)] via the 33-distinct-row decomposition of the central-mask
// basis: no RK staging (16KB/tile), no rel MFMAs (10/wave/tile), no prl
// scratch/gather. MFMAs 42->32 per wave-tile; LDS traffic ~ -25%.
// Schedule (2 barriers/tile, every drain covered by compute):
//   S MFMAs on Kl  ->  pS gather (Dl/LUT, static)  ->  bar#1 (drains V(ch))
//   issue K(ch+1)  ->  softmax+Pp                  (covers K DMA)
//   PV MFMAs on Vl ->  bar#2 (drains K(ch+1))      ->  issue V(ch+1)
// LDS [50176B]: K[64]x128B @0, V[192]x128B @8192, D[64][40]bf16 @32768,
//   LUT[3072]u8 @37888, per-wave Pp bf16[16][72] @40960.  3 blocks/CU.
// XOR swizzle (K/V): 16B chunk c of row r stored at physical chunk c^(r&7).
// ---------------------------------------------------------------------------
__global__ __launch_bounds__(256, 3) void attn_mfma(
    const ushort* __restrict__ qb, const ushort* __restrict__ kb,
    const ushort* __restrict__ vtb, const ushort* __restrict__ Db,
    const unsigned char* __restrict__ lutb,
    const float* __restrict__ rwb,
    ushort* __restrict__ op0, ushort* __restrict__ op1,
    float2* __restrict__ mlb) {
  __shared__ __align__(16) char smem[50176];
  ushort* Kl = (ushort*)smem;                        // [64] rows x 128B
  ushort* Vl = (ushort*)(smem + 8192);               // [192] rows x 128B
  ushort* Dl = (ushort*)(smem + 32768);              // [64][40] bf16
  unsigned char* Ll = (unsigned char*)(smem + 37888);// [3072] u8

  const int L  = blockIdx.x + 24 * blockIdx.y + 192 * blockIdx.z;
  const int h  = L & 7;                     // XCD id under round-robin
  const int g  = L >> 3;
  const int bsk = g / 24;
  const int b  = bsk >> 1;
  const int sk = bsk & 1;
  const int t0 = (g - bsk * 24) * 64;
  const int bT = b * Tn;
  const int tid = threadIdx.x;
  const int w = tid >> 6, lane = tid & 63, quad = lane >> 4, ln = lane & 15;

  ushort* Pp = (ushort*)(smem + 40960 + w * 2304);   // [16][72] bf16 per wave

  const int lr  = lane >> 3;          // staging: row-in-chunk 0..7
  const int lcx = (lane & 7) ^ lr;    // staging: logical 16B chunk (swizzle)

  // ---- prologue staging: K(0), V(0), Dl, LUT ----
  {
    const int s0 = sk * 768;
#pragma unroll
    for (int i = 0; i < 2; i++) {
      int kc = w * 2 + i, sr = kc * 8 + lr;
      gld_lds16(kb + (size_t)(bT + s0 + sr) * 512 + h * 64 + lcx * 8,
                (ushort*)(smem + kc * 1024) + lane * 8);
    }
#pragma unroll
    for (int i = 0; i < 6; i++) {
      int kc = w * 6 + i, vr = kc * 8 + lr;
      gld_lds16(vtb + (size_t)(h * 192 + vr) * 3072 + bT + s0 + lcx * 8,
                (ushort*)(smem + 8192 + kc * 1024) + lane * 8);
    }
    const ushort* dsrc = Db + ((size_t)(b * 8 + h) * 1536 + t0) * 40;
    gld_lds16(dsrc + w * 512 + lane * 8,
              (ushort*)(smem + 32768 + w * 1024) + lane * 8);
    if (w == 0)
      gld_lds16(dsrc + 4 * 512 + lane * 8,
                (ushort*)(smem + 32768 + 4096) + lane * 8);
    if (w < 3)
      gld_lds16((const ushort*)(lutb + w * 1024) + lane * 8,
                (ushort*)(smem + 37888 + w * 1024) + lane * 8);
  }

  // Q fragments (A-layout m=ln, k=quad*8+ks*32+e) + content bias
  short8 qw8[2];
  {
    const ushort* qrow = qb + (size_t)(bT + t0 + 16 * w + ln) * 512 + h * 64;
#pragma unroll
    for (int ks = 0; ks < 2; ks++) {
      int k0 = quad * 8 + ks * 32;
#pragma unroll
      for (int e = 0; e < 8; e++)
        qw8[ks][e] = (short)f2bs(bs2f(qrow[k0 + e]) + rwb[h * 64 + k0 + e]);
    }
  }

  f32x4 Oacc[12];
  float m_i[4], l_i[4];
#pragma unroll
  for (int vt = 0; vt < 12; vt++) Oacc[vt] = (f32x4){0.f, 0.f, 0.f, 0.f};
#pragma unroll
  for (int r = 0; r < 4; r++) { m_i[r] = -1e30f; l_i[r] = 0.f; }

  __syncthreads();   // K(0)/V(0)/Dl/LUT staged

  const int ibase = sk * 768 - t0 - 16 * w - 4 * quad + ln + 1535;
  const int tl0 = 16 * w + 4 * quad;

  for (int ch = 0; ch < 12; ch++) {
    const int s0 = sk * 768 + ch * 64;

    // ---- S phase: content logits (reads Kl) ----
    f32x4 Sacc[4];
    __builtin_amdgcn_s_setprio(1);
#pragma unroll
    for (int ct = 0; ct < 4; ct++) {
      Sacc[ct] = (f32x4){0.f, 0.f, 0.f, 0.f};
#pragma unroll
      for (int ks = 0; ks < 2; ks++) {
        short8 bfr = *(const short8*)(
            Kl + (16 * ct + ln) * 64 + ((quad + 4 * ks) ^ (ln & 7)) * 8);
        Sacc[ct] = __builtin_amdgcn_mfma_f32_16x16x32_bf16(qw8[ks], bfr, Sacc[ct], 0, 0, 0);
      }
    }
    __builtin_amdgcn_s_setprio(0);

    // ---- rel logits via D-lookup (static Dl/Ll; idx = s-t+1535) ----
    float pS[4][4];
#pragma unroll
    for (int ct = 0; ct < 4; ct++)
#pragma unroll
      for (int r = 0; r < 4; r++) {
        int idx = ibase + 64 * ch + 16 * ct - r;
        int u = Ll[idx];
        pS[ct][r] = Sacc[ct][r] + bs2f(Dl[(tl0 + r) * 40 + u]);
      }

    __syncthreads();   // #1: Kl free (S reads done); V(ch) drained into LDS

    // ---- issue K(ch+1) DMA (covered by softmax + PV) ----
    if (ch < 11) {
      const int s0n = s0 + 64;
#pragma unroll
      for (int i = 0; i < 2; i++) {
        int kc = w * 2 + i, sr = kc * 8 + lr;
        gld_lds16(kb + (size_t)(bT + s0n + sr) * 512 + h * 64 + lcx * 8,
                  (ushort*)(smem + kc * 1024) + lane * 8);
      }
    }

    // ---- online softmax (row lives in the 16 lanes of this quad) ----
    float alpha[4];
#pragma unroll
    for (int r = 0; r < 4; r++) {
      float mx = fmaxf(fmaxf(pS[0][r], pS[1][r]), fmaxf(pS[2][r], pS[3][r]));
#pragma unroll
      for (int off = 8; off >= 1; off >>= 1) mx = fmaxf(mx, __shfl_xor(mx, off));
      float mnew = fmaxf(m_i[r], mx);
      alpha[r] = __expf(m_i[r] - mnew);
      m_i[r] = mnew;
      float rs = 0.f;
#pragma unroll
      for (int ct = 0; ct < 4; ct++) {
        pS[ct][r] = __expf(pS[ct][r] - mnew);
        rs += pS[ct][r];
      }
#pragma unroll
      for (int off = 8; off >= 1; off >>= 1) rs += __shfl_xor(rs, off);
      l_i[r] = l_i[r] * alpha[r] + rs;
    }
#pragma unroll
    for (int vt = 0; vt < 12; vt++)
#pragma unroll
      for (int r = 0; r < 4; r++) Oacc[vt][r] *= alpha[r];
    // probs -> Pp (bf16, per-wave scratch; same-wave RAW via lgkmcnt)
#pragma unroll
    for (int ct = 0; ct < 4; ct++)
#pragma unroll
      for (int r = 0; r < 4; r++)
        Pp[(4 * quad + r) * 72 + 16 * ct + ln] = f2bs(pS[ct][r]);
    __asm__ volatile("s_waitcnt lgkmcnt(0)" ::: "memory");

    // ---- PV phase (reads Vl + Pp; covers K(ch+1) DMA latency) ----
    short8 afr[2];
#pragma unroll
    for (int ks = 0; ks < 2; ks++)
      afr[ks] = *(const short8*)(Pp + ln * 72 + quad * 8 + ks * 32);
    __builtin_amdgcn_s_setprio(1);
#pragma unroll
    for (int vt = 0; vt < 12; vt++) {
#pragma unroll
      for (int ks = 0; ks < 2; ks++) {
        short8 bfr = *(const short8*)(
            Vl + (16 * vt + ln) * 64 + ((quad + 4 * ks) ^ (ln & 7)) * 8);
        Oacc[vt] = __builtin_amdgcn_mfma_f32_16x16x32_bf16(afr[ks], bfr, Oacc[vt], 0, 0, 0);
      }
    }
    __builtin_amdgcn_s_setprio(0);

    __syncthreads();   // #2: Vl free (PV done); K(ch+1) drained

    // ---- issue V(ch+1) DMA (covered by next S + gather) ----
    if (ch < 11) {
      const int s0n = s0 + 64;
#pragma unroll
      for (int i = 0; i < 6; i++) {
        int kc = w * 6 + i, vr = kc * 8 + lr;
        gld_lds16(vtb + (size_t)(h * 192 + vr) * 3072 + bT + s0n + lcx * 8,
                  (ushort*)(smem + 8192 + kc * 1024) + lane * 8);
      }
    }
  }

  // epilogue: normalized bf16 partial + (m,l)
  ushort* op = sk ? op1 : op0;
  float inv[4];
#pragma unroll
  for (int r = 0; r < 4; r++) inv[r] = 1.f / l_i[r];
#pragma unroll
  for (int vt = 0; vt < 12; vt++)
#pragma unroll
    for (int r = 0; r < 4; r++) {
      int t = t0 + 16 * w + 4 * quad + r;
      op[(size_t)(bT + t) * 1536 + h * 192 + 16 * vt + ln] = f2bs(Oacc[vt][r] * inv[r]);
    }
  if (ln == 0) {
#pragma unroll
    for (int r = 0; r < 4; r++) {
      int t = t0 + 16 * w + 4 * quad + r;
      float2 v; v.x = m_i[r]; v.y = l_i[r];
      mlb[((sk * 2 + b) * 8 + h) * 1536 + t] = v;
    }
  }
}

// ---------------------------------------------------------------------------
// Combine the two split-K partials: O = sum_i e^{m_i-M} l_i O_i / sum e^{m-M} l
// ---------------------------------------------------------------------------
__global__ __launch_bounds__(256) void attn_combine(
    const ushort* __restrict__ op0, const ushort* __restrict__ op1,
    const float2* __restrict__ mlb, ushort* __restrict__ att) {
  int g = blockIdx.x * 256 + threadIdx.x;   // group of 4 bf16
  int row = g / 384;                        // 0..3071
  int c4 = (g - row * 384) * 4;             // 0..1532
  int b = row >= 1536;
  int t = row - b * 1536;
  int h = c4 / 192;
  float2 ml0 = mlb[((0 + b) * 8 + h) * 1536 + t];
  float2 ml1 = mlb[((2 + b) * 8 + h) * 1536 + t];
  float M = fmaxf(ml0.x, ml1.x);
  float w0 = __expf(ml0.x - M) * ml0.y;
  float w1 = __expf(ml1.x - M) * ml1.y;
  float inv = 1.f / (w0 + w1);
  w0 *= inv; w1 *= inv;
  size_t off = (size_t)row * 1536 + c4;
  uint2 a = *(const uint2*)(op0 + off);
  uint2 c = *(const uint2*)(op1 + off);
  uint2 o;
  float r0 = w0 * bs2f((ushort)(a.x & 0xffff)) + w1 * bs2f((ushort)(c.x & 0xffff));
  float r1 = w0 * bs2f((ushort)(a.x >> 16))    + w1 * bs2f((ushort)(c.x >> 16));
  float r2 = w0 * bs2f((ushort)(a.y & 0xffff)) + w1 * bs2f((ushort)(c.y & 0xffff));
  float r3 = w0 * bs2f((ushort)(a.y >> 16))    + w1 * bs2f((ushort)(c.y >> 16));
  o.x = (uint)f2bs(r0) | ((uint)f2bs(r1) << 16);
  o.y = (uint)f2bs(r2) | ((uint)f2bs(r3) << 16);
  *(uint2*)(att + off) = o;
}

// ---------------------------------------------------------------------------
extern "C" void kernel_launch(void* const* d_in, const int* in_sizes, int n_in,
                              void* d_out, int out_size, void* d_ws, size_t ws_size,
                              hipStream_t stream) {
  const float* x   = (const float*)d_in[0];
  const float* Wq  = (const float*)d_in[1];
  const float* Wk  = (const float*)d_in[2];
  const float* Wv  = (const float*)d_in[3];
  const float* Wr  = (const float*)d_in[4];
  const float* rwb = (const float*)d_in[5];
  const float* rrb = (const float*)d_in[6];
  const float* Wo  = (const float*)d_in[7];
  const float* bo  = (const float*)d_in[8];
  float* out = (float*)d_out;

  char* ws = (char*)d_ws;
  // Region A [0, 9437184): xb (prep->qkv) -> op1 (attn) -> att (combine, same
  // addresses elementwise) -> gemm_out input.
  ushort* xb  = (ushort*)ws;
  ushort* op1 = (ushort*)ws;
  ushort* att = (ushort*)ws;
  ushort* Wot = (ushort*)(ws + 9437184);    // [1536][1536] bf16, until gemm_out
  ushort* Wt  = (ushort*)(ws + 14155776);   // [2560][1536] bf16, until gemm_qkv
  ushort* op0 = (ushort*)(ws + 14155776);   // overlays dead Wt (attn phase)
  ushort* qb  = (ushort*)(ws + 23592960);   // [3072][512] bf16 (scaled)
  ushort* kb  = (ushort*)(ws + 26738688);   // [3072][512] bf16
  ushort* vtb = (ushort*)(ws + 29884416);   // [1536][3072] bf16 (V^T)
  // former rkb region [39321600, 42467328) recycled:
  ushort* Db   = (ushort*)(ws + 39321600);  // [2][8][1536][40] bf16 (1.97MB)
  unsigned char* lutb = (unsigned char*)(ws + 41287680);  // [3072] u8
  ushort* rkdb = (ushort*)(ws + 41290752);  // [8][40][64] bf16 (40KB)
  float2* mlb = (float2*)(ws + 42467328);   // [2][2][8][1536] (m,l)

  prep<<<dim3(48, 48, 6), dim3(256), 0, stream>>>(
      x, Wq, Wk, Wv, Wo, Wr, xb, Wt, Wot, rkdb, lutb);
  gemm_qkv<<<dim3(20, 24), dim3(256), 0, stream>>>(xb, Wt, qb, kb, vtb);
  dgemm<<<dim3(24, 8, 2), dim3(256), 0, stream>>>(qb, rrb, rkdb, Db);
  attn_mfma<<<dim3(24, 8, 4), dim3(256), 0, stream>>>(
      qb, kb, vtb, Db, lutb, rwb, op0, op1, mlb);
  attn_combine<<<dim3(4608), dim3(256), 0, stream>>>(op0, op1, mlb, att);
  gemm_out<<<dim3(12, 24), dim3(256), 0, stream>>>(att, Wot, bo, out);
}

// Round 5
// 236.179 us; speedup vs baseline: 1.2656x; 1.0763x over previous
//
#include <hip/hip_runtime.h>
#include <hip/hip_bf16.h>

typedef __hip_bfloat16 bf16;
typedef unsigned short ushort;
typedef unsigned int uint;
typedef __attribute__((ext_vector_type(8))) short short8;
typedef __attribute__((ext_vector_type(4))) float f32x4;

#define Bsz 2
#define Tn  1536
#define Cn  1536
#define Hn  8
#define Kn  64
#define Vn  192
// H*K = 512, H*V = 1536, 2T-1 = 3071

__device__ __forceinline__ ushort f2bs(float f) {
  union { bf16 h; ushort u; } cv;
  cv.h = __float2bfloat16(f);
  return cv.u;
}
__device__ __forceinline__ float bs2f(ushort u) {
  union { float f; uint v; } cv; cv.v = ((uint)u) << 16; return cv.f;
}

// async global->LDS, 16B per lane; LDS dest = wave-uniform base + lane*16
__device__ __forceinline__ void gld_lds16(const ushort* g, ushort* l) {
  __builtin_amdgcn_global_load_lds(
      (const __attribute__((address_space(1))) uint*)g,
      (__attribute__((address_space(3))) uint*)l, 16, 0, 0);
}

// ---------------------------------------------------------------------------
// Merged prep kernel, grid (48,48,6):
//  z=0..3: transpose+cvt  W{q,k,v,o} f32 [1536][Cc] -> bf16 [Cc][1536]
//  z=4   : x f32 -> xb bf16 (vectorized x4, grid-stride)
//  z=5   : rkd[8][40][64] bf16 (33 DISTINCT rel-basis rows per head: the
//          central-mask basis is a step function of |d| -> only 16 buckets
//          x sign +-, + d=0; rows 33..39 are ZERO pad) and lutb[3072] u8:
//          d+1535 -> row index u. Same double-precision width math as the
//          original rkb builder (no comparison flips vs fp32 ref).
// ---------------------------------------------------------------------------
__global__ __launch_bounds__(256) void prep(
    const float* __restrict__ x,  const float* __restrict__ Wq,
    const float* __restrict__ Wk, const float* __restrict__ Wv,
    const float* __restrict__ Wo, const float* __restrict__ Wr,
    ushort* __restrict__ xb, ushort* __restrict__ Wt,
    ushort* __restrict__ Wot, ushort* __restrict__ rkdb,
    unsigned char* __restrict__ lutb) {
  const int z = blockIdx.z;
  if (z < 4) {
    if (z < 2 && blockIdx.x >= 16) return;
    const float* in = (z == 0) ? Wq : (z == 1) ? Wk : (z == 2) ? Wv : Wo;
    ushort* out = (z == 0) ? Wt : (z == 1) ? Wt + 512 * 1536
                : (z == 2) ? Wt + 1024 * 1536 : Wot;
    const int Cc = (z < 2) ? 512 : 1536;
    __shared__ float tile[32][33];
    const int bx = blockIdx.x * 32;
    const int by = blockIdx.y * 32;
    const int tx = threadIdx.x & 31, ty = threadIdx.x >> 5;
#pragma unroll
    for (int i = 0; i < 32; i += 8)
      tile[ty + i][tx] = in[(size_t)(by + ty + i) * Cc + bx + tx];
    __syncthreads();
#pragma unroll
    for (int i = 0; i < 32; i += 8)
      out[(size_t)(bx + ty + i) * 1536 + by + tx] = f2bs(tile[tx][ty + i]);
  } else if (z == 4) {
    const int n4 = 3072 * 1536 / 4;
    for (int i = (blockIdx.y * 48 + blockIdx.x) * 256 + threadIdx.x; i < n4;
         i += 2304 * 256) {
      float4 v = ((const float4*)x)[i];
      uint2 o;
      o.x = (uint)f2bs(v.x) | ((uint)f2bs(v.y) << 16);
      o.y = (uint)f2bs(v.z) | ((uint)f2bs(v.w) << 16);
      ((uint2*)xb)[i] = o;
    }
  } else {
    const int base = (blockIdx.y * 48 + blockIdx.x) * 256 + threadIdx.x;
    if (base < 8 * 40 * 64) {
      // rkd entry: h, u-row (pad 33..39 = 0), k
      const int h = base / 2560, rem = base % 2560, u = rem >> 6, k = rem & 63;
      float acc = 0.f;
      if (u < 33) {
        const float sg = (u == 32) ? 0.f : (u < 16 ? 1.f : -1.f);
        const int c = (u == 32) ? 16 : (u < 16 ? u + 1 : u - 15);
        // active features are the c LARGEST widths: i = 16-c .. 15 (ascending,
        // same summation order as the original rkb builder)
#pragma unroll
        for (int i = 0; i < 16; i++)
          if (i >= 16 - c)
            acc += Wr[i * 512 + h * 64 + k] + sg * Wr[(16 + i) * 512 + h * 64 + k];
      }
      rkdb[h * 2560 + u * 64 + k] = f2bs(acc);
    } else if (base < 8 * 40 * 64 + 3072) {
      const int idx = base - 8 * 40 * 64;       // 0..3071 (3071 = pad)
      const int d = idx - 1535;
      const float ad = fabsf((float)d);
      int c = 0;
#pragma unroll
      for (int i = 0; i < 16; i++) {
        double cw = exp(log((double)(Tn + 1)) * (double)(i + 1) / 16.0) - 1.0;
        if ((float)cw > ad) c++;
      }
      lutb[idx] = (unsigned char)((d == 0) ? 32 : (d > 0 ? c - 1 : 15 + c));
    }
  }
}

// ---------------------------------------------------------------------------
// Fused QKV MFMA GEMM: xb @ Wt^T-layout -> qb/kb/vtb (m97 structure).
// ---------------------------------------------------------------------------
__global__ __launch_bounds__(256) void gemm_qkv(
    const ushort* __restrict__ xb, const ushort* __restrict__ Wt,
    ushort* __restrict__ qb, ushort* __restrict__ kb, ushort* __restrict__ vtb) {
  __shared__ ushort Al[128 * 32];
  __shared__ ushort Bl[128 * 32];
  const int tid = threadIdx.x;
  const int w = tid >> 6, lane = tid & 63, quad = lane >> 4, ln = lane & 15;
  const int bm = blockIdx.y * 128, bn = blockIdx.x * 128;
  const int wm = (w & 1) * 64, wn = (w >> 1) * 64;
  f32x4 acc[4][4];
#pragma unroll
  for (int i = 0; i < 4; i++)
#pragma unroll
    for (int j = 0; j < 4; j++) acc[i][j] = (f32x4){0.f, 0.f, 0.f, 0.f};

  for (int k0 = 0; k0 < 1536; k0 += 32) {
    __syncthreads();
#pragma unroll
    for (int st = 0; st < 2; st++) {
      int idx = tid + st * 256;
      int row = idx >> 2, col = (idx & 3) * 8;
      gld_lds16(xb + (size_t)(bm + row) * 1536 + k0 + col, Al + idx * 8);
      gld_lds16(Wt + (size_t)(bn + row) * 1536 + k0 + col, Bl + idx * 8);
    }
    __syncthreads();
    short8 af[4], bfr[4];
#pragma unroll
    for (int t = 0; t < 4; t++) {
      af[t]  = *(const short8*)(Al + (wm + t * 16 + ln) * 32 + quad * 8);
      bfr[t] = *(const short8*)(Bl + (wn + t * 16 + ln) * 32 + quad * 8);
    }
#pragma unroll
    for (int mt = 0; mt < 4; mt++)
#pragma unroll
      for (int nt = 0; nt < 4; nt++)
        acc[mt][nt] = __builtin_amdgcn_mfma_f32_16x16x32_bf16(
            af[mt], bfr[nt], acc[mt][nt], 0, 0, 0);
  }

  if (bn < 512) {
#pragma unroll
    for (int mt = 0; mt < 4; mt++)
#pragma unroll
      for (int nt = 0; nt < 4; nt++)
#pragma unroll
        for (int r = 0; r < 4; r++) {
          int m = bm + wm + mt * 16 + quad * 4 + r;
          int n = bn + wn + nt * 16 + ln;
          qb[(size_t)m * 512 + n] = f2bs(acc[mt][nt][r] * 0.125f);
        }
  } else if (bn < 1024) {
#pragma unroll
    for (int mt = 0; mt < 4; mt++)
#pragma unroll
      for (int nt = 0; nt < 4; nt++)
#pragma unroll
        for (int r = 0; r < 4; r++) {
          int m = bm + wm + mt * 16 + quad * 4 + r;
          int n = bn - 512 + wn + nt * 16 + ln;
          kb[(size_t)m * 512 + n] = f2bs(acc[mt][nt][r]);
        }
  } else {
#pragma unroll
    for (int mt = 0; mt < 4; mt++)
#pragma unroll
      for (int nt = 0; nt < 4; nt++) {
        int vcol = bn - 1024 + wn + nt * 16 + ln;
        int m0 = bm + wm + mt * 16 + quad * 4;
        uint2 val;
        val.x = (uint)f2bs(acc[mt][nt][0]) | ((uint)f2bs(acc[mt][nt][1]) << 16);
        val.y = (uint)f2bs(acc[mt][nt][2]) | ((uint)f2bs(acc[mt][nt][3]) << 16);
        *(uint2*)(vtb + (size_t)vcol * 3072 + m0) = val;
      }
  }
}

// ---------------------------------------------------------------------------
// Output MFMA GEMM: att(bf16) @ Wot + bo -> f32 out.
// ---------------------------------------------------------------------------
__global__ __launch_bounds__(256) void gemm_out(
    const ushort* __restrict__ att, const ushort* __restrict__ Wot,
    const float* __restrict__ bo, float* __restrict__ out) {
  __shared__ ushort Al[128 * 32];
  __shared__ ushort Bl[128 * 32];
  const int tid = threadIdx.x;
  const int w = tid >> 6, lane = tid & 63, quad = lane >> 4, ln = lane & 15;
  const int bm = blockIdx.y * 128, bn = blockIdx.x * 128;
  const int wm = (w & 1) * 64, wn = (w >> 1) * 64;
  f32x4 acc[4][4];
#pragma unroll
  for (int i = 0; i < 4; i++)
#pragma unroll
    for (int j = 0; j < 4; j++) acc[i][j] = (f32x4){0.f, 0.f, 0.f, 0.f};

  for (int k0 = 0; k0 < 1536; k0 += 32) {
    __syncthreads();
#pragma unroll
    for (int st = 0; st < 2; st++) {
      int idx = tid + st * 256;
      int row = idx >> 2, col = (idx & 3) * 8;
      gld_lds16(att + (size_t)(bm + row) * 1536 + k0 + col, Al + idx * 8);
      gld_lds16(Wot + (size_t)(bn + row) * 1536 + k0 + col, Bl + idx * 8);
    }
    __syncthreads();
    short8 af[4], bfr[4];
#pragma unroll
    for (int t = 0; t < 4; t++) {
      af[t]  = *(const short8*)(Al + (wm + t * 16 + ln) * 32 + quad * 8);
      bfr[t] = *(const short8*)(Bl + (wn + t * 16 + ln) * 32 + quad * 8);
    }
#pragma unroll
    for (int mt = 0; mt < 4; mt++)
#pragma unroll
      for (int nt = 0; nt < 4; nt++)
        acc[mt][nt] = __builtin_amdgcn_mfma_f32_16x16x32_bf16(
            af[mt], bfr[nt], acc[mt][nt], 0, 0, 0);
  }
#pragma unroll
  for (int mt = 0; mt < 4; mt++)
#pragma unroll
    for (int nt = 0; nt < 4; nt++)
#pragma unroll
      for (int r = 0; r < 4; r++) {
        int m = bm + wm + mt * 16 + quad * 4 + r;
        int n = bn + wn + nt * 16 + ln;
        out[(size_t)m * 1536 + n] = acc[mt][nt][r] + bo[n];
      }
}

// ---------------------------------------------------------------------------
// MFMA flash attention, split-K(x2), t-tile 64, 4 waves, DMA staging.
// XCD-AWARE SWIZZLE: linear block id L -> xcd = L&7 owns head h = xcd only.
//
// v5 (resubmit; round-4 bench was an infra failure, no counters):
// dgemm kernel ELIMINATED — D[t][u] = (q+rrb).rkd[u] is computed in the
// prologue with 6 MFMAs (A = q+rrb fragments, B = rkd[h] rows direct from
// global L2; rows 33..39 of rkd are zeros so the row-clamp is safe), written
// straight to the Dl LDS region. Removes a serial dispatch + 2MB Db traffic.
// Schedule (softmax BEFORE bar#1 so the big V drain gets the long coverage
// window; K, 3x smaller, gets the PV window):
//   S MFMAs on Kl -> gather (Dl/Ll) -> softmax -> Pp/afr
//   bar#1 (drains V(ch); Kl free) -> issue K(ch+1)
//   PV MFMAs on Vl (covers K DMA)
//   bar#2 (drains K(ch+1); Vl free) -> issue V(ch+1)
// LDS [50176B]: K[64]x128B @0, V[192]x128B @8192, D[64][40]bf16 @32768,
//   LUT[3072]u8 @37888, per-wave Pp bf16[16][72] @40960.  3 blocks/CU.
// XOR swizzle (K/V): 16B chunk c of row r stored at physical chunk c^(r&7).
// ---------------------------------------------------------------------------
__global__ __launch_bounds__(256, 3) void attn_mfma(
    const ushort* __restrict__ qb, const ushort* __restrict__ kb,
    const ushort* __restrict__ vtb, const ushort* __restrict__ rkdb,
    const unsigned char* __restrict__ lutb,
    const float* __restrict__ rwb, const float* __restrict__ rrb,
    ushort* __restrict__ op0, ushort* __restrict__ op1,
    float2* __restrict__ mlb) {
  __shared__ __align__(16) char smem[50176];
  ushort* Kl = (ushort*)smem;                        // [64] rows x 128B
  ushort* Vl = (ushort*)(smem + 8192);               // [192] rows x 128B
  ushort* Dl = (ushort*)(smem + 32768);              // [64][40] bf16
  unsigned char* Ll = (unsigned char*)(smem + 37888);// [3072] u8

  const int L  = blockIdx.x + 24 * blockIdx.y + 192 * blockIdx.z;
  const int h  = L & 7;                     // XCD id under round-robin
  const int g  = L >> 3;
  const int bsk = g / 24;
  const int b  = bsk >> 1;
  const int sk = bsk & 1;
  const int t0 = (g - bsk * 24) * 64;
  const int bT = b * Tn;
  const int tid = threadIdx.x;
  const int w = tid >> 6, lane = tid & 63, quad = lane >> 4, ln = lane & 15;

  ushort* Pp = (ushort*)(smem + 40960 + w * 2304);   // [16][72] bf16 per wave

  const int lr  = lane >> 3;          // staging: row-in-chunk 0..7
  const int lcx = (lane & 7) ^ lr;    // staging: logical 16B chunk (swizzle)

  // ---- prologue staging: K(0), V(0), LUT ----
  {
    const int s0 = sk * 768;
#pragma unroll
    for (int i = 0; i < 2; i++) {
      int kc = w * 2 + i, sr = kc * 8 + lr;
      gld_lds16(kb + (size_t)(bT + s0 + sr) * 512 + h * 64 + lcx * 8,
                (ushort*)(smem + kc * 1024) + lane * 8);
    }
#pragma unroll
    for (int i = 0; i < 6; i++) {
      int kc = w * 6 + i, vr = kc * 8 + lr;
      gld_lds16(vtb + (size_t)(h * 192 + vr) * 3072 + bT + s0 + lcx * 8,
                (ushort*)(smem + 8192 + kc * 1024) + lane * 8);
    }
    if (w < 3)
      gld_lds16((const ushort*)(lutb + w * 1024) + lane * 8,
                (ushort*)(smem + 37888 + w * 1024) + lane * 8);
  }

  // Q fragments (A-layout m=ln, k=quad*8+ks*32+e): content bias + rel bias
  short8 qw8[2], qr8[2];
  {
    const ushort* qrow = qb + (size_t)(bT + t0 + 16 * w + ln) * 512 + h * 64;
#pragma unroll
    for (int ks = 0; ks < 2; ks++) {
      int k0 = quad * 8 + ks * 32;
#pragma unroll
      for (int e = 0; e < 8; e++) {
        float qv = bs2f(qrow[k0 + e]);
        qw8[ks][e] = (short)f2bs(qv + rwb[h * 64 + k0 + e]);
        qr8[ks][e] = (short)f2bs(qv + rrb[h * 64 + k0 + e]);
      }
    }
  }

  // ---- D table via MFMA: D[t][u] = (q+rrb) . rkd[h][u], u<33 (pad rows=0) --
  {
    f32x4 Dacc[3];
#pragma unroll
    for (int ut = 0; ut < 3; ut++) {
      Dacc[ut] = (f32x4){0.f, 0.f, 0.f, 0.f};
#pragma unroll
      for (int ks = 0; ks < 2; ks++) {
        int urow = 16 * ut + ln; urow = urow > 39 ? 39 : urow;  // rows>=33 are 0
        short8 bfr = *(const short8*)(rkdb + h * 2560 + urow * 64 + quad * 8 + ks * 32);
        Dacc[ut] = __builtin_amdgcn_mfma_f32_16x16x32_bf16(qr8[ks], bfr, Dacc[ut], 0, 0, 0);
      }
    }
    const int trow = 16 * w + 4 * quad;   // wave-local t rows (C: m=4*quad+r)
#pragma unroll
    for (int ut = 0; ut < 2; ut++)
#pragma unroll
      for (int r = 0; r < 4; r++)
        Dl[(trow + r) * 40 + 16 * ut + ln] = f2bs(Dacc[ut][r]);
    if (ln == 0) {
#pragma unroll
      for (int r = 0; r < 4; r++)
        Dl[(trow + r) * 40 + 32] = f2bs(Dacc[2][r]);
    }
  }

  f32x4 Oacc[12];
  float m_i[4], l_i[4];
#pragma unroll
  for (int vt = 0; vt < 12; vt++) Oacc[vt] = (f32x4){0.f, 0.f, 0.f, 0.f};
#pragma unroll
  for (int r = 0; r < 4; r++) { m_i[r] = -1e30f; l_i[r] = 0.f; }

  __syncthreads();   // K(0)/V(0)/LUT staged; Dl writes visible

  const int ibase = sk * 768 - t0 - 16 * w - 4 * quad + ln + 1535;
  const int tl0 = 16 * w + 4 * quad;

  for (int ch = 0; ch < 12; ch++) {
    // ---- rel lookups (Dl/Ll static; independent of S MFMAs) ----
    float dval[4][4];
#pragma unroll
    for (int ct = 0; ct < 4; ct++)
#pragma unroll
      for (int r = 0; r < 4; r++) {
        int idx = ibase + 64 * ch + 16 * ct - r;
        dval[ct][r] = bs2f(Dl[(tl0 + r) * 40 + Ll[idx]]);
      }

    // ---- S phase: content logits (reads Kl) ----
    f32x4 Sacc[4];
    __builtin_amdgcn_s_setprio(1);
#pragma unroll
    for (int ct = 0; ct < 4; ct++) {
      Sacc[ct] = (f32x4){0.f, 0.f, 0.f, 0.f};
#pragma unroll
      for (int ks = 0; ks < 2; ks++) {
        short8 bfr = *(const short8*)(
            Kl + (16 * ct + ln) * 64 + ((quad + 4 * ks) ^ (ln & 7)) * 8);
        Sacc[ct] = __builtin_amdgcn_mfma_f32_16x16x32_bf16(qw8[ks], bfr, Sacc[ct], 0, 0, 0);
      }
    }
    __builtin_amdgcn_s_setprio(0);

    float pS[4][4];
#pragma unroll
    for (int ct = 0; ct < 4; ct++)
#pragma unroll
      for (int r = 0; r < 4; r++)
        pS[ct][r] = Sacc[ct][r] + dval[ct][r];

    // ---- online softmax BEFORE bar#1 (covers the V(ch) DMA drain) ----
    float alpha[4];
#pragma unroll
    for (int r = 0; r < 4; r++) {
      float mx = fmaxf(fmaxf(pS[0][r], pS[1][r]), fmaxf(pS[2][r], pS[3][r]));
#pragma unroll
      for (int off = 8; off >= 1; off >>= 1) mx = fmaxf(mx, __shfl_xor(mx, off));
      float mnew = fmaxf(m_i[r], mx);
      alpha[r] = __expf(m_i[r] - mnew);
      m_i[r] = mnew;
      float rs = 0.f;
#pragma unroll
      for (int ct = 0; ct < 4; ct++) {
        pS[ct][r] = __expf(pS[ct][r] - mnew);
        rs += pS[ct][r];
      }
#pragma unroll
      for (int off = 8; off >= 1; off >>= 1) rs += __shfl_xor(rs, off);
      l_i[r] = l_i[r] * alpha[r] + rs;
    }
#pragma unroll
    for (int vt = 0; vt < 12; vt++)
#pragma unroll
      for (int r = 0; r < 4; r++) Oacc[vt][r] *= alpha[r];
    // probs -> Pp (bf16, per-wave scratch; same-wave RAW via lgkmcnt)
#pragma unroll
    for (int ct = 0; ct < 4; ct++)
#pragma unroll
      for (int r = 0; r < 4; r++)
        Pp[(4 * quad + r) * 72 + 16 * ct + ln] = f2bs(pS[ct][r]);
    __asm__ volatile("s_waitcnt lgkmcnt(0)" ::: "memory");
    short8 afr[2];
#pragma unroll
    for (int ks = 0; ks < 2; ks++)
      afr[ks] = *(const short8*)(Pp + ln * 72 + quad * 8 + ks * 32);

    __syncthreads();   // #1: Kl free (S done); V(ch) drained into LDS

    // ---- issue K(ch+1) DMA (covered by PV) ----
    if (ch < 11) {
      const int s0n = sk * 768 + ch * 64 + 64;
#pragma unroll
      for (int i = 0; i < 2; i++) {
        int kc = w * 2 + i, sr = kc * 8 + lr;
        gld_lds16(kb + (size_t)(bT + s0n + sr) * 512 + h * 64 + lcx * 8,
                  (ushort*)(smem + kc * 1024) + lane * 8);
      }
    }

    // ---- PV phase (reads Vl + afr; covers K(ch+1) DMA latency) ----
    __builtin_amdgcn_s_setprio(1);
#pragma unroll
    for (int vt = 0; vt < 12; vt++) {
#pragma unroll
      for (int ks = 0; ks < 2; ks++) {
        short8 bfr = *(const short8*)(
            Vl + (16 * vt + ln) * 64 + ((quad + 4 * ks) ^ (ln & 7)) * 8);
        Oacc[vt] = __builtin_amdgcn_mfma_f32_16x16x32_bf16(afr[ks], bfr, Oacc[vt], 0, 0, 0);
      }
    }
    __builtin_amdgcn_s_setprio(0);

    __syncthreads();   // #2: Vl free (PV done); K(ch+1) drained

    // ---- issue V(ch+1) DMA (covered by next S + gather + softmax) ----
    if (ch < 11) {
      const int s0n = sk * 768 + ch * 64 + 64;
#pragma unroll
      for (int i = 0; i < 6; i++) {
        int kc = w * 6 + i, vr = kc * 8 + lr;
        gld_lds16(vtb + (size_t)(h * 192 + vr) * 3072 + bT + s0n + lcx * 8,
                  (ushort*)(smem + 8192 + kc * 1024) + lane * 8);
      }
    }
  }

  // epilogue: normalized bf16 partial + (m,l)
  ushort* op = sk ? op1 : op0;
  float inv[4];
#pragma unroll
  for (int r = 0; r < 4; r++) inv[r] = 1.f / l_i[r];
#pragma unroll
  for (int vt = 0; vt < 12; vt++)
#pragma unroll
    for (int r = 0; r < 4; r++) {
      int t = t0 + 16 * w + 4 * quad + r;
      op[(size_t)(bT + t) * 1536 + h * 192 + 16 * vt + ln] = f2bs(Oacc[vt][r] * inv[r]);
    }
  if (ln == 0) {
#pragma unroll
    for (int r = 0; r < 4; r++) {
      int t = t0 + 16 * w + 4 * quad + r;
      float2 v; v.x = m_i[r]; v.y = l_i[r];
      mlb[((sk * 2 + b) * 8 + h) * 1536 + t] = v;
    }
  }
}

// ---------------------------------------------------------------------------
// Combine the two split-K partials: O = sum_i e^{m_i-M} l_i O_i / sum e^{m-M} l
// ---------------------------------------------------------------------------
__global__ __launch_bounds__(256) void attn_combine(
    const ushort* __restrict__ op0, const ushort* __restrict__ op1,
    const float2* __restrict__ mlb, ushort* __restrict__ att) {
  int g = blockIdx.x * 256 + threadIdx.x;   // group of 4 bf16
  int row = g / 384;                        // 0..3071
  int c4 = (g - row * 384) * 4;             // 0..1532
  int b = row >= 1536;
  int t = row - b * 1536;
  int h = c4 / 192;
  float2 ml0 = mlb[((0 + b) * 8 + h) * 1536 + t];
  float2 ml1 = mlb[((2 + b) * 8 + h) * 1536 + t];
  float M = fmaxf(ml0.x, ml1.x);
  float w0 = __expf(ml0.x - M) * ml0.y;
  float w1 = __expf(ml1.x - M) * ml1.y;
  float inv = 1.f / (w0 + w1);
  w0 *= inv; w1 *= inv;
  size_t off = (size_t)row * 1536 + c4;
  uint2 a = *(const uint2*)(op0 + off);
  uint2 c = *(const uint2*)(op1 + off);
  uint2 o;
  float r0 = w0 * bs2f((ushort)(a.x & 0xffff)) + w1 * bs2f((ushort)(c.x & 0xffff));
  float r1 = w0 * bs2f((ushort)(a.x >> 16))    + w1 * bs2f((ushort)(c.x >> 16));
  float r2 = w0 * bs2f((ushort)(a.y & 0xffff)) + w1 * bs2f((ushort)(c.y & 0xffff));
  float r3 = w0 * bs2f((ushort)(a.y >> 16))    + w1 * bs2f((ushort)(c.y >> 16));
  o.x = (uint)f2bs(r0) | ((uint)f2bs(r1) << 16);
  o.y = (uint)f2bs(r2) | ((uint)f2bs(r3) << 16);
  *(uint2*)(att + off) = o;
}

// ---------------------------------------------------------------------------
extern "C" void kernel_launch(void* const* d_in, const int* in_sizes, int n_in,
                              void* d_out, int out_size, void* d_ws, size_t ws_size,
                              hipStream_t stream) {
  const float* x   = (const float*)d_in[0];
  const float* Wq  = (const float*)d_in[1];
  const float* Wk  = (const float*)d_in[2];
  const float* Wv  = (const float*)d_in[3];
  const float* Wr  = (const float*)d_in[4];
  const float* rwb = (const float*)d_in[5];
  const float* rrb = (const float*)d_in[6];
  const float* Wo  = (const float*)d_in[7];
  const float* bo  = (const float*)d_in[8];
  float* out = (float*)d_out;

  char* ws = (char*)d_ws;
  // Region A [0, 9437184): xb (prep->qkv) -> op1 (attn) -> att (combine, same
  // addresses elementwise) -> gemm_out input.
  ushort* xb  = (ushort*)ws;
  ushort* op1 = (ushort*)ws;
  ushort* att = (ushort*)ws;
  ushort* Wot = (ushort*)(ws + 9437184);    // [1536][1536] bf16, until gemm_out
  ushort* Wt  = (ushort*)(ws + 14155776);   // [2560][1536] bf16, until gemm_qkv
  ushort* op0 = (ushort*)(ws + 14155776);   // overlays dead Wt (attn phase)
  ushort* qb  = (ushort*)(ws + 23592960);   // [3072][512] bf16 (scaled)
  ushort* kb  = (ushort*)(ws + 26738688);   // [3072][512] bf16
  ushort* vtb = (ushort*)(ws + 29884416);   // [1536][3072] bf16 (V^T)
  unsigned char* lutb = (unsigned char*)(ws + 41287680);  // [3072] u8
  ushort* rkdb = (ushort*)(ws + 41290752);  // [8][40][64] bf16 (40KB)
  float2* mlb = (float2*)(ws + 42467328);   // [2][2][8][1536] (m,l)

  prep<<<dim3(48, 48, 6), dim3(256), 0, stream>>>(
      x, Wq, Wk, Wv, Wo, Wr, xb, Wt, Wot, rkdb, lutb);
  gemm_qkv<<<dim3(20, 24), dim3(256), 0, stream>>>(xb, Wt, qb, kb, vtb);
  attn_mfma<<<dim3(24, 8, 4), dim3(256), 0, stream>>>(
      qb, kb, vtb, rkdb, lutb, rwb, rrb, op0, op1, mlb);
  attn_combine<<<dim3(4608), dim3(256), 0, stream>>>(op0, op1, mlb, att);
  gemm_out<<<dim3(12, 24), dim3(256), 0, stream>>>(att, Wot, bo, out);
}

// Round 6
// 224.342 us; speedup vs baseline: 1.3323x; 1.0528x over previous
//
#include <hip/hip_runtime.h>
#include <hip/hip_bf16.h>

typedef __hip_bfloat16 bf16;
typedef unsigned short ushort;
typedef unsigned int uint;
typedef __attribute__((ext_vector_type(8))) short short8;
typedef __attribute__((ext_vector_type(4))) float f32x4;

#define Bsz 2
#define Tn  1536
#define Cn  1536
#define Hn  8
#define Kn  64
#define Vn  192
// H*K = 512, H*V = 1536, 2T-1 = 3071

__device__ __forceinline__ ushort f2bs(float f) {
  union { bf16 h; ushort u; } cv;
  cv.h = __float2bfloat16(f);
  return cv.u;
}
__device__ __forceinline__ float bs2f(ushort u) {
  union { float f; uint v; } cv; cv.v = ((uint)u) << 16; return cv.f;
}

// async global->LDS, 16B per lane; LDS dest = wave-uniform base + lane*16
__device__ __forceinline__ void gld_lds16(const ushort* g, ushort* l) {
  __builtin_amdgcn_global_load_lds(
      (const __attribute__((address_space(1))) uint*)g,
      (__attribute__((address_space(3))) uint*)l, 16, 0, 0);
}

// 16-lane max-reduce step via DPP (VALU-rate, no LDS): x = max(x, dpp(x))
#define DPP_MAXSTEP(x, ctrl)                                                  \
  do {                                                                        \
    union { float f; int i; } a_, b_;                                         \
    a_.f = (x);                                                               \
    b_.i = __builtin_amdgcn_update_dpp(a_.i, a_.i, (ctrl), 0xf, 0xf, true);   \
    (x) = fmaxf((x), b_.f);                                                   \
  } while (0)

// ---------------------------------------------------------------------------
// Merged prep kernel, grid (48,48,6):
//  z=0..3: transpose+cvt  W{q,k,v,o} f32 [1536][Cc] -> bf16 [Cc][1536]
//  z=4   : x f32 -> xb bf16 (vectorized x4, grid-stride)
//  z=5   : rkd[8][40][64] bf16 (33 DISTINCT rel-basis rows per head: the
//          central-mask basis is a step function of |d| -> only 16 buckets
//          x sign +-, + d=0; rows 33..39 are ZERO pad) and lutb[3072] u8:
//          d+1535 -> row index u. Same double-precision width math as the
//          original rkb builder (no comparison flips vs fp32 ref).
// ---------------------------------------------------------------------------
__global__ __launch_bounds__(256) void prep(
    const float* __restrict__ x,  const float* __restrict__ Wq,
    const float* __restrict__ Wk, const float* __restrict__ Wv,
    const float* __restrict__ Wo, const float* __restrict__ Wr,
    ushort* __restrict__ xb, ushort* __restrict__ Wt,
    ushort* __restrict__ Wot, ushort* __restrict__ rkdb,
    unsigned char* __restrict__ lutb) {
  const int z = blockIdx.z;
  if (z < 4) {
    if (z < 2 && blockIdx.x >= 16) return;
    const float* in = (z == 0) ? Wq : (z == 1) ? Wk : (z == 2) ? Wv : Wo;
    ushort* out = (z == 0) ? Wt : (z == 1) ? Wt + 512 * 1536
                : (z == 2) ? Wt + 1024 * 1536 : Wot;
    const int Cc = (z < 2) ? 512 : 1536;
    __shared__ float tile[32][33];
    const int bx = blockIdx.x * 32;
    const int by = blockIdx.y * 32;
    const int tx = threadIdx.x & 31, ty = threadIdx.x >> 5;
#pragma unroll
    for (int i = 0; i < 32; i += 8)
      tile[ty + i][tx] = in[(size_t)(by + ty + i) * Cc + bx + tx];
    __syncthreads();
#pragma unroll
    for (int i = 0; i < 32; i += 8)
      out[(size_t)(bx + ty + i) * 1536 + by + tx] = f2bs(tile[tx][ty + i]);
  } else if (z == 4) {
    const int n4 = 3072 * 1536 / 4;
    for (int i = (blockIdx.y * 48 + blockIdx.x) * 256 + threadIdx.x; i < n4;
         i += 2304 * 256) {
      float4 v = ((const float4*)x)[i];
      uint2 o;
      o.x = (uint)f2bs(v.x) | ((uint)f2bs(v.y) << 16);
      o.y = (uint)f2bs(v.z) | ((uint)f2bs(v.w) << 16);
      ((uint2*)xb)[i] = o;
    }
  } else {
    const int base = (blockIdx.y * 48 + blockIdx.x) * 256 + threadIdx.x;
    if (base < 8 * 40 * 64) {
      // rkd entry: h, u-row (pad 33..39 = 0), k
      const int h = base / 2560, rem = base % 2560, u = rem >> 6, k = rem & 63;
      float acc = 0.f;
      if (u < 33) {
        const float sg = (u == 32) ? 0.f : (u < 16 ? 1.f : -1.f);
        const int c = (u == 32) ? 16 : (u < 16 ? u + 1 : u - 15);
        // active features are the c LARGEST widths: i = 16-c .. 15 (ascending,
        // same summation order as the original rkb builder)
#pragma unroll
        for (int i = 0; i < 16; i++)
          if (i >= 16 - c)
            acc += Wr[i * 512 + h * 64 + k] + sg * Wr[(16 + i) * 512 + h * 64 + k];
      }
      rkdb[h * 2560 + u * 64 + k] = f2bs(acc);
    } else if (base < 8 * 40 * 64 + 3072) {
      const int idx = base - 8 * 40 * 64;       // 0..3071 (3071 = pad)
      const int d = idx - 1535;
      const float ad = fabsf((float)d);
      int c = 0;
#pragma unroll
      for (int i = 0; i < 16; i++) {
        double cw = exp(log((double)(Tn + 1)) * (double)(i + 1) / 16.0) - 1.0;
        if ((float)cw > ad) c++;
      }
      lutb[idx] = (unsigned char)((d == 0) ? 32 : (d > 0 ? c - 1 : 15 + c));
    }
  }
}

// ---------------------------------------------------------------------------
// Fused QKV MFMA GEMM: xb @ Wt^T-layout -> qb/kb/vtb (m97 structure).
// ---------------------------------------------------------------------------
__global__ __launch_bounds__(256) void gemm_qkv(
    const ushort* __restrict__ xb, const ushort* __restrict__ Wt,
    ushort* __restrict__ qb, ushort* __restrict__ kb, ushort* __restrict__ vtb) {
  __shared__ ushort Al[128 * 32];
  __shared__ ushort Bl[128 * 32];
  const int tid = threadIdx.x;
  const int w = tid >> 6, lane = tid & 63, quad = lane >> 4, ln = lane & 15;
  const int bm = blockIdx.y * 128, bn = blockIdx.x * 128;
  const int wm = (w & 1) * 64, wn = (w >> 1) * 64;
  f32x4 acc[4][4];
#pragma unroll
  for (int i = 0; i < 4; i++)
#pragma unroll
    for (int j = 0; j < 4; j++) acc[i][j] = (f32x4){0.f, 0.f, 0.f, 0.f};

  for (int k0 = 0; k0 < 1536; k0 += 32) {
    __syncthreads();
#pragma unroll
    for (int st = 0; st < 2; st++) {
      int idx = tid + st * 256;
      int row = idx >> 2, col = (idx & 3) * 8;
      gld_lds16(xb + (size_t)(bm + row) * 1536 + k0 + col, Al + idx * 8);
      gld_lds16(Wt + (size_t)(bn + row) * 1536 + k0 + col, Bl + idx * 8);
    }
    __syncthreads();
    short8 af[4], bfr[4];
#pragma unroll
    for (int t = 0; t < 4; t++) {
      af[t]  = *(const short8*)(Al + (wm + t * 16 + ln) * 32 + quad * 8);
      bfr[t] = *(const short8*)(Bl + (wn + t * 16 + ln) * 32 + quad * 8);
    }
#pragma unroll
    for (int mt = 0; mt < 4; mt++)
#pragma unroll
      for (int nt = 0; nt < 4; nt++)
        acc[mt][nt] = __builtin_amdgcn_mfma_f32_16x16x32_bf16(
            af[mt], bfr[nt], acc[mt][nt], 0, 0, 0);
  }

  if (bn < 512) {
#pragma unroll
    for (int mt = 0; mt < 4; mt++)
#pragma unroll
      for (int nt = 0; nt < 4; nt++)
#pragma unroll
        for (int r = 0; r < 4; r++) {
          int m = bm + wm + mt * 16 + quad * 4 + r;
          int n = bn + wn + nt * 16 + ln;
          qb[(size_t)m * 512 + n] = f2bs(acc[mt][nt][r] * 0.125f);
        }
  } else if (bn < 1024) {
#pragma unroll
    for (int mt = 0; mt < 4; mt++)
#pragma unroll
      for (int nt = 0; nt < 4; nt++)
#pragma unroll
        for (int r = 0; r < 4; r++) {
          int m = bm + wm + mt * 16 + quad * 4 + r;
          int n = bn - 512 + wn + nt * 16 + ln;
          kb[(size_t)m * 512 + n] = f2bs(acc[mt][nt][r]);
        }
  } else {
#pragma unroll
    for (int mt = 0; mt < 4; mt++)
#pragma unroll
      for (int nt = 0; nt < 4; nt++) {
        int vcol = bn - 1024 + wn + nt * 16 + ln;
        int m0 = bm + wm + mt * 16 + quad * 4;
        uint2 val;
        val.x = (uint)f2bs(acc[mt][nt][0]) | ((uint)f2bs(acc[mt][nt][1]) << 16);
        val.y = (uint)f2bs(acc[mt][nt][2]) | ((uint)f2bs(acc[mt][nt][3]) << 16);
        *(uint2*)(vtb + (size_t)vcol * 3072 + m0) = val;
      }
  }
}

// ---------------------------------------------------------------------------
// Output MFMA GEMM: att(bf16) @ Wot + bo -> f32 out.
// ---------------------------------------------------------------------------
__global__ __launch_bounds__(256) void gemm_out(
    const ushort* __restrict__ att, const ushort* __restrict__ Wot,
    const float* __restrict__ bo, float* __restrict__ out) {
  __shared__ ushort Al[128 * 32];
  __shared__ ushort Bl[128 * 32];
  const int tid = threadIdx.x;
  const int w = tid >> 6, lane = tid & 63, quad = lane >> 4, ln = lane & 15;
  const int bm = blockIdx.y * 128, bn = blockIdx.x * 128;
  const int wm = (w & 1) * 64, wn = (w >> 1) * 64;
  f32x4 acc[4][4];
#pragma unroll
  for (int i = 0; i < 4; i++)
#pragma unroll
    for (int j = 0; j < 4; j++) acc[i][j] = (f32x4){0.f, 0.f, 0.f, 0.f};

  for (int k0 = 0; k0 < 1536; k0 += 32) {
    __syncthreads();
#pragma unroll
    for (int st = 0; st < 2; st++) {
      int idx = tid + st * 256;
      int row = idx >> 2, col = (idx & 3) * 8;
      gld_lds16(att + (size_t)(bm + row) * 1536 + k0 + col, Al + idx * 8);
      gld_lds16(Wot + (size_t)(bn + row) * 1536 + k0 + col, Bl + idx * 8);
    }
    __syncthreads();
    short8 af[4], bfr[4];
#pragma unroll
    for (int t = 0; t < 4; t++) {
      af[t]  = *(const short8*)(Al + (wm + t * 16 + ln) * 32 + quad * 8);
      bfr[t] = *(const short8*)(Bl + (wn + t * 16 + ln) * 32 + quad * 8);
    }
#pragma unroll
    for (int mt = 0; mt < 4; mt++)
#pragma unroll
      for (int nt = 0; nt < 4; nt++)
        acc[mt][nt] = __builtin_amdgcn_mfma_f32_16x16x32_bf16(
            af[mt], bfr[nt], acc[mt][nt], 0, 0, 0);
  }
#pragma unroll
  for (int mt = 0; mt < 4; mt++)
#pragma unroll
    for (int nt = 0; nt < 4; nt++)
#pragma unroll
      for (int r = 0; r < 4; r++) {
        int m = bm + wm + mt * 16 + quad * 4 + r;
        int n = bn + wn + nt * 16 + ln;
        out[(size_t)m * 1536 + n] = acc[mt][nt][r] + bo[n];
      }
}

// ---------------------------------------------------------------------------
// MFMA flash attention, split-K(x2), t-tile 64, 4 waves, DMA staging.
// XCD-AWARE SWIZZLE: linear block id L -> xcd = L&7 owns head h = xcd only.
//
// v6: softmax cross-lane latency removed (v5 was dependency-chain bound:
// 8 ds_bpermute ~60-100cy each per row). (a) 16-lane MAX reduce now uses 4
// DPP steps (quad_perm xor1/xor2, row_ror:4, row_ror:8 — VALU rate).
// (b) row SUM eliminated: Lacc = mfma(P_frag, ones, Lacc) accumulates
// l = l*alpha + sum(P) via the matrix pipe (every C column = row sum).
// Schedule unchanged from v5:
//   gather (Dl/Ll) -> S MFMAs on Kl -> softmax(DPP) -> Pp/afr
//   bar#1 (drains V(ch); Kl free) -> issue K(ch+1)
//   PV+Lacc MFMAs on Vl (covers K DMA)
//   bar#2 (drains K(ch+1); Vl free) -> issue V(ch+1)
// D[t][u] = (q+rrb).rkd[u] built in prologue with 6 MFMAs (rkd direct from L2).
// LDS [50176B]: K[64]x128B @0, V[192]x128B @8192, D[64][40]bf16 @32768,
//   LUT[3072]u8 @37888, per-wave Pp bf16[16][72] @40960.  3 blocks/CU.
// XOR swizzle (K/V): 16B chunk c of row r stored at physical chunk c^(r&7).
// ---------------------------------------------------------------------------
__global__ __launch_bounds__(256, 3) void attn_mfma(
    const ushort* __restrict__ qb, const ushort* __restrict__ kb,
    const ushort* __restrict__ vtb, const ushort* __restrict__ rkdb,
    const unsigned char* __restrict__ lutb,
    const float* __restrict__ rwb, const float* __restrict__ rrb,
    ushort* __restrict__ op0, ushort* __restrict__ op1,
    float2* __restrict__ mlb) {
  __shared__ __align__(16) char smem[50176];
  ushort* Kl = (ushort*)smem;                        // [64] rows x 128B
  ushort* Vl = (ushort*)(smem + 8192);               // [192] rows x 128B
  ushort* Dl = (ushort*)(smem + 32768);              // [64][40] bf16
  unsigned char* Ll = (unsigned char*)(smem + 37888);// [3072] u8

  const int L  = blockIdx.x + 24 * blockIdx.y + 192 * blockIdx.z;
  const int h  = L & 7;                     // XCD id under round-robin
  const int g  = L >> 3;
  const int bsk = g / 24;
  const int b  = bsk >> 1;
  const int sk = bsk & 1;
  const int t0 = (g - bsk * 24) * 64;
  const int bT = b * Tn;
  const int tid = threadIdx.x;
  const int w = tid >> 6, lane = tid & 63, quad = lane >> 4, ln = lane & 15;

  ushort* Pp = (ushort*)(smem + 40960 + w * 2304);   // [16][72] bf16 per wave

  const int lr  = lane >> 3;          // staging: row-in-chunk 0..7
  const int lcx = (lane & 7) ^ lr;    // staging: logical 16B chunk (swizzle)

  // ---- prologue staging: K(0), V(0), LUT ----
  {
    const int s0 = sk * 768;
#pragma unroll
    for (int i = 0; i < 2; i++) {
      int kc = w * 2 + i, sr = kc * 8 + lr;
      gld_lds16(kb + (size_t)(bT + s0 + sr) * 512 + h * 64 + lcx * 8,
                (ushort*)(smem + kc * 1024) + lane * 8);
    }
#pragma unroll
    for (int i = 0; i < 6; i++) {
      int kc = w * 6 + i, vr = kc * 8 + lr;
      gld_lds16(vtb + (size_t)(h * 192 + vr) * 3072 + bT + s0 + lcx * 8,
                (ushort*)(smem + 8192 + kc * 1024) + lane * 8);
    }
    if (w < 3)
      gld_lds16((const ushort*)(lutb + w * 1024) + lane * 8,
                (ushort*)(smem + 37888 + w * 1024) + lane * 8);
  }

  // Q fragments (A-layout m=ln, k=quad*8+ks*32+e): content bias + rel bias
  short8 qw8[2], qr8[2];
  {
    const ushort* qrow = qb + (size_t)(bT + t0 + 16 * w + ln) * 512 + h * 64;
#pragma unroll
    for (int ks = 0; ks < 2; ks++) {
      int k0 = quad * 8 + ks * 32;
#pragma unroll
      for (int e = 0; e < 8; e++) {
        float qv = bs2f(qrow[k0 + e]);
        qw8[ks][e] = (short)f2bs(qv + rwb[h * 64 + k0 + e]);
        qr8[ks][e] = (short)f2bs(qv + rrb[h * 64 + k0 + e]);
      }
    }
  }

  // ---- D table via MFMA: D[t][u] = (q+rrb) . rkd[h][u], u<33 (pad rows=0) --
  {
    f32x4 Dacc[3];
#pragma unroll
    for (int ut = 0; ut < 3; ut++) {
      Dacc[ut] = (f32x4){0.f, 0.f, 0.f, 0.f};
#pragma unroll
      for (int ks = 0; ks < 2; ks++) {
        int urow = 16 * ut + ln; urow = urow > 39 ? 39 : urow;  // rows>=33 are 0
        short8 bfr = *(const short8*)(rkdb + h * 2560 + urow * 64 + quad * 8 + ks * 32);
        Dacc[ut] = __builtin_amdgcn_mfma_f32_16x16x32_bf16(qr8[ks], bfr, Dacc[ut], 0, 0, 0);
      }
    }
    const int trow = 16 * w + 4 * quad;   // wave-local t rows (C: m=4*quad+r)
#pragma unroll
    for (int ut = 0; ut < 2; ut++)
#pragma unroll
      for (int r = 0; r < 4; r++)
        Dl[(trow + r) * 40 + 16 * ut + ln] = f2bs(Dacc[ut][r]);
    if (ln == 0) {
#pragma unroll
      for (int r = 0; r < 4; r++)
        Dl[(trow + r) * 40 + 32] = f2bs(Dacc[2][r]);
    }
  }

  f32x4 Oacc[12];
  f32x4 Lacc = (f32x4){0.f, 0.f, 0.f, 0.f};   // online l via ones-MFMA
  float m_i[4];
#pragma unroll
  for (int vt = 0; vt < 12; vt++) Oacc[vt] = (f32x4){0.f, 0.f, 0.f, 0.f};
#pragma unroll
  for (int r = 0; r < 4; r++) m_i[r] = -1e30f;

  short8 ones8;
#pragma unroll
  for (int e = 0; e < 8; e++) ones8[e] = (short)0x3F80;   // bf16 1.0

  __syncthreads();   // K(0)/V(0)/LUT staged; Dl writes visible

  const int ibase = sk * 768 - t0 - 16 * w - 4 * quad + ln + 1535;
  const int tl0 = 16 * w + 4 * quad;

  for (int ch = 0; ch < 12; ch++) {
    // ---- rel lookups (Dl/Ll static; independent of S MFMAs) ----
    float dval[4][4];
#pragma unroll
    for (int ct = 0; ct < 4; ct++)
#pragma unroll
      for (int r = 0; r < 4; r++) {
        int idx = ibase + 64 * ch + 16 * ct - r;
        dval[ct][r] = bs2f(Dl[(tl0 + r) * 40 + Ll[idx]]);
      }

    // ---- S phase: content logits (reads Kl) ----
    f32x4 Sacc[4];
    __builtin_amdgcn_s_setprio(1);
#pragma unroll
    for (int ct = 0; ct < 4; ct++) {
      Sacc[ct] = (f32x4){0.f, 0.f, 0.f, 0.f};
#pragma unroll
      for (int ks = 0; ks < 2; ks++) {
        short8 bfr = *(const short8*)(
            Kl + (16 * ct + ln) * 64 + ((quad + 4 * ks) ^ (ln & 7)) * 8);
        Sacc[ct] = __builtin_amdgcn_mfma_f32_16x16x32_bf16(qw8[ks], bfr, Sacc[ct], 0, 0, 0);
      }
    }
    __builtin_amdgcn_s_setprio(0);

    float pS[4][4];
#pragma unroll
    for (int ct = 0; ct < 4; ct++)
#pragma unroll
      for (int r = 0; r < 4; r++)
        pS[ct][r] = Sacc[ct][r] + dval[ct][r];

    // ---- online softmax: DPP max-reduce (no LDS), sum via ones-MFMA ----
    float alpha[4];
#pragma unroll
    for (int r = 0; r < 4; r++) {
      float mx = fmaxf(fmaxf(pS[0][r], pS[1][r]), fmaxf(pS[2][r], pS[3][r]));
      DPP_MAXSTEP(mx, 0xB1);    // quad_perm [1,0,3,2]  (xor 1)
      DPP_MAXSTEP(mx, 0x4E);    // quad_perm [2,3,0,1]  (xor 2)
      DPP_MAXSTEP(mx, 0x124);   // row_ror:4
      DPP_MAXSTEP(mx, 0x128);   // row_ror:8
      float mnew = fmaxf(m_i[r], mx);
      alpha[r] = __expf(m_i[r] - mnew);
      m_i[r] = mnew;
#pragma unroll
      for (int ct = 0; ct < 4; ct++)
        pS[ct][r] = __expf(pS[ct][r] - mnew);
    }
#pragma unroll
    for (int vt = 0; vt < 12; vt++)
#pragma unroll
      for (int r = 0; r < 4; r++) Oacc[vt][r] *= alpha[r];
#pragma unroll
    for (int r = 0; r < 4; r++) Lacc[r] *= alpha[r];
    // probs -> Pp (bf16, per-wave scratch; same-wave RAW via lgkmcnt)
#pragma unroll
    for (int ct = 0; ct < 4; ct++)
#pragma unroll
      for (int r = 0; r < 4; r++)
        Pp[(4 * quad + r) * 72 + 16 * ct + ln] = f2bs(pS[ct][r]);
    __asm__ volatile("s_waitcnt lgkmcnt(0)" ::: "memory");
    short8 afr[2];
#pragma unroll
    for (int ks = 0; ks < 2; ks++)
      afr[ks] = *(const short8*)(Pp + ln * 72 + quad * 8 + ks * 32);

    __syncthreads();   // #1: Kl free (S done); V(ch) drained into LDS

    // ---- issue K(ch+1) DMA (covered by PV) ----
    if (ch < 11) {
      const int s0n = sk * 768 + ch * 64 + 64;
#pragma unroll
      for (int i = 0; i < 2; i++) {
        int kc = w * 2 + i, sr = kc * 8 + lr;
        gld_lds16(kb + (size_t)(bT + s0n + sr) * 512 + h * 64 + lcx * 8,
                  (ushort*)(smem + kc * 1024) + lane * 8);
      }
    }

    // ---- PV phase (reads Vl + afr; covers K(ch+1) DMA latency) ----
    __builtin_amdgcn_s_setprio(1);
    // l += sum(P) per row (every C column = row sum; read any ln)
    Lacc = __builtin_amdgcn_mfma_f32_16x16x32_bf16(afr[0], ones8, Lacc, 0, 0, 0);
    Lacc = __builtin_amdgcn_mfma_f32_16x16x32_bf16(afr[1], ones8, Lacc, 0, 0, 0);
#pragma unroll
    for (int vt = 0; vt < 12; vt++) {
#pragma unroll
      for (int ks = 0; ks < 2; ks++) {
        short8 bfr = *(const short8*)(
            Vl + (16 * vt + ln) * 64 + ((quad + 4 * ks) ^ (ln & 7)) * 8);
        Oacc[vt] = __builtin_amdgcn_mfma_f32_16x16x32_bf16(afr[ks], bfr, Oacc[vt], 0, 0, 0);
      }
    }
    __builtin_amdgcn_s_setprio(0);

    __syncthreads();   // #2: Vl free (PV done); K(ch+1) drained

    // ---- issue V(ch+1) DMA (covered by next S + gather + softmax) ----
    if (ch < 11) {
      const int s0n = sk * 768 + ch * 64 + 64;
#pragma unroll
      for (int i = 0; i < 6; i++) {
        int kc = w * 6 + i, vr = kc * 8 + lr;
        gld_lds16(vtb + (size_t)(h * 192 + vr) * 3072 + bT + s0n + lcx * 8,
                  (ushort*)(smem + 8192 + kc * 1024) + lane * 8);
      }
    }
  }

  // epilogue: normalized bf16 partial + (m,l);  l = Lacc (all cols equal)
  ushort* op = sk ? op1 : op0;
  float inv[4];
#pragma unroll
  for (int r = 0; r < 4; r++) inv[r] = 1.f / Lacc[r];
#pragma unroll
  for (int vt = 0; vt < 12; vt++)
#pragma unroll
    for (int r = 0; r < 4; r++) {
      int t = t0 + 16 * w + 4 * quad + r;
      op[(size_t)(bT + t) * 1536 + h * 192 + 16 * vt + ln] = f2bs(Oacc[vt][r] * inv[r]);
    }
  if (ln == 0) {
#pragma unroll
    for (int r = 0; r < 4; r++) {
      int t = t0 + 16 * w + 4 * quad + r;
      float2 v; v.x = m_i[r]; v.y = Lacc[r];
      mlb[((sk * 2 + b) * 8 + h) * 1536 + t] = v;
    }
  }
}

// ---------------------------------------------------------------------------
// Combine the two split-K partials: O = sum_i e^{m_i-M} l_i O_i / sum e^{m-M} l
// ---------------------------------------------------------------------------
__global__ __launch_bounds__(256) void attn_combine(
    const ushort* __restrict__ op0, const ushort* __restrict__ op1,
    const float2* __restrict__ mlb, ushort* __restrict__ att) {
  int g = blockIdx.x * 256 + threadIdx.x;   // group of 4 bf16
  int row = g / 384;                        // 0..3071
  int c4 = (g - row * 384) * 4;             // 0..1532
  int b = row >= 1536;
  int t = row - b * 1536;
  int h = c4 / 192;
  float2 ml0 = mlb[((0 + b) * 8 + h) * 1536 + t];
  float2 ml1 = mlb[((2 + b) * 8 + h) * 1536 + t];
  float M = fmaxf(ml0.x, ml1.x);
  float w0 = __expf(ml0.x - M) * ml0.y;
  float w1 = __expf(ml1.x - M) * ml1.y;
  float inv = 1.f / (w0 + w1);
  w0 *= inv; w1 *= inv;
  size_t off = (size_t)row * 1536 + c4;
  uint2 a = *(const uint2*)(op0 + off);
  uint2 c = *(const uint2*)(op1 + off);
  uint2 o;
  float r0 = w0 * bs2f((ushort)(a.x & 0xffff)) + w1 * bs2f((ushort)(c.x & 0xffff));
  float r1 = w0 * bs2f((ushort)(a.x >> 16))    + w1 * bs2f((ushort)(c.x >> 16));
  float r2 = w0 * bs2f((ushort)(a.y & 0xffff)) + w1 * bs2f((ushort)(c.y & 0xffff));
  float r3 = w0 * bs2f((ushort)(a.y >> 16))    + w1 * bs2f((ushort)(c.y >> 16));
  o.x = (uint)f2bs(r0) | ((uint)f2bs(r1) << 16);
  o.y = (uint)f2bs(r2) | ((uint)f2bs(r3) << 16);
  *(uint2*)(att + off) = o;
}

// ---------------------------------------------------------------------------
extern "C" void kernel_launch(void* const* d_in, const int* in_sizes, int n_in,
                              void* d_out, int out_size, void* d_ws, size_t ws_size,
                              hipStream_t stream) {
  const float* x   = (const float*)d_in[0];
  const float* Wq  = (const float*)d_in[1];
  const float* Wk  = (const float*)d_in[2];
  const float* Wv  = (const float*)d_in[3];
  const float* Wr  = (const float*)d_in[4];
  const float* rwb = (const float*)d_in[5];
  const float* rrb = (const float*)d_in[6];
  const float* Wo  = (const float*)d_in[7];
  const float* bo  = (const float*)d_in[8];
  float* out = (float*)d_out;

  char* ws = (char*)d_ws;
  // Region A [0, 9437184): xb (prep->qkv) -> op1 (attn) -> att (combine, same
  // addresses elementwise) -> gemm_out input.
  ushort* xb  = (ushort*)ws;
  ushort* op1 = (ushort*)ws;
  ushort* att = (ushort*)ws;
  ushort* Wot = (ushort*)(ws + 9437184);    // [1536][1536] bf16, until gemm_out
  ushort* Wt  = (ushort*)(ws + 14155776);   // [2560][1536] bf16, until gemm_qkv
  ushort* op0 = (ushort*)(ws + 14155776);   // overlays dead Wt (attn phase)
  ushort* qb  = (ushort*)(ws + 23592960);   // [3072][512] bf16 (scaled)
  ushort* kb  = (ushort*)(ws + 26738688);   // [3072][512] bf16
  ushort* vtb = (ushort*)(ws + 29884416);   // [1536][3072] bf16 (V^T)
  unsigned char* lutb = (unsigned char*)(ws + 41287680);  // [3072] u8
  ushort* rkdb = (ushort*)(ws + 41290752);  // [8][40][64] bf16 (40KB)
  float2* mlb = (float2*)(ws + 42467328);   // [2][2][8][1536] (m,l)

  prep<<<dim3(48, 48, 6), dim3(256), 0, stream>>>(
      x, Wq, Wk, Wv, Wo, Wr, xb, Wt, Wot, rkdb, lutb);
  gemm_qkv<<<dim3(20, 24), dim3(256), 0, stream>>>(xb, Wt, qb, kb, vtb);
  attn_mfma<<<dim3(24, 8, 4), dim3(256), 0, stream>>>(
      qb, kb, vtb, rkdb, lutb, rwb, rrb, op0, op1, mlb);
  attn_combine<<<dim3(4608), dim3(256), 0, stream>>>(op0, op1, mlb, att);
  gemm_out<<<dim3(12, 24), dim3(256), 0, stream>>>(att, Wot, bo, out);
}